// Round 6
// baseline (9480.076 us; speedup 1.0000x reference)
//
#include <hip/hip_runtime.h>
#include <hip/hip_bf16.h>
#include <cstdint>
#include <cstddef>

static constexpr int NN = 102400;   // nodes
static constexpr int EE = 819200;   // edges
static constexpr int DD = 120;      // input channels
static constexpr int HH = 200;      // hidden
static constexpr int LL = 400;      // nodes per graph
static constexpr int BB = 256;      // graphs
static constexpr int NSTEPS = 8;

typedef __attribute__((ext_vector_type(8))) short short8;
typedef __attribute__((ext_vector_type(4))) float f32x4;

__device__ __forceinline__ unsigned short f2bf(float f) {
  union { float f; unsigned u; } v; v.f = f;
  return (unsigned short)((v.u + 0x7fffu + ((v.u >> 16) & 1u)) >> 16);
}
__device__ __forceinline__ float bf2f(unsigned short s) {
  union { unsigned u; float f; } v; v.u = ((unsigned)s) << 16; return v.f;
}

// ---------------------------------------------------------------------------
// Generic MFMA GEMM (setup / conv / head paths).
// ---------------------------------------------------------------------------
template<int AMODE, int ASRC, int OBF, int RELU, int EPI>
__global__ __launch_bounds__(256) void gemm_mfma(
    const void* __restrict__ Asrc, const void* __restrict__ A2,
    const short* __restrict__ WP, const float* __restrict__ bias,
    void* __restrict__ Cdst, int M, int Nout, int K, int KT,
    const float* __restrict__ tt0, const float* __restrict__ tt1,
    const float* __restrict__ cnt2, float* __restrict__ hout,
    unsigned short* __restrict__ hbout)
{
  __shared__ short Asm[4096];
  __shared__ short Bsm[4096];
  const int tid = threadIdx.x;
  const int row0 = blockIdx.y * 128;
  const int col0 = blockIdx.x * 128;

  f32x4 acc[4][4];
#pragma unroll
  for (int mi = 0; mi < 4; mi++)
#pragma unroll
    for (int ni = 0; ni < 4; ni++) acc[mi][ni] = (f32x4){0.f, 0.f, 0.f, 0.f};

  const int r = tid & 15;
  const int kgl = (tid >> 4) & 3;
  const int ghalf = tid >> 6;
  const int w = tid >> 6, l = tid & 63;
  const int wr = w >> 1, wc = w & 1;

  for (int t = 0; t < KT; t++) {
#pragma unroll
    for (int half = 0; half < 2; half++) {
      const int g = ghalf + half * 4;
      int row = row0 + g * 16 + r;
      if (row >= M) row = M - 1;
      const int k0 = t * 32 + kgl * 8;
      short8 sv;
      bool direct = false;
      if (AMODE == 0 && ASRC == 1) {
        if (k0 < K) {
          sv = *reinterpret_cast<const short8*>(
              (const unsigned short*)Asrc + (size_t)row * K + k0);
          direct = true;
        }
      } else if (AMODE == 1) {
        if (k0 < K) {
          const int b = row / 398, tt = row - b * 398;
          const int tap = k0 / 200, i0 = k0 - tap * 200;
          sv = *reinterpret_cast<const short8*>(
              (const unsigned short*)Asrc + ((size_t)(b * 400 + tt + tap)) * 200 + i0);
          direct = true;
        }
      } else if (AMODE == 2) {
        if (k0 < K) {
          const int b = row / 398, tt = row - b * 398;
          const int tap = k0 / 320, c0 = k0 - tap * 320;
          const int node = b * 400 + tt + tap;
          if (c0 < 120) {
            const float* p = (const float*)A2 + (size_t)node * 120 + c0;
            const float4 x0 = *reinterpret_cast<const float4*>(p);
            const float4 x1 = *reinterpret_cast<const float4*>(p + 4);
            sv[0] = (short)f2bf(x0.x); sv[1] = (short)f2bf(x0.y);
            sv[2] = (short)f2bf(x0.z); sv[3] = (short)f2bf(x0.w);
            sv[4] = (short)f2bf(x1.x); sv[5] = (short)f2bf(x1.y);
            sv[6] = (short)f2bf(x1.z); sv[7] = (short)f2bf(x1.w);
            direct = true;
          } else {
            sv = *reinterpret_cast<const short8*>(
                (const unsigned short*)Asrc + (size_t)node * 200 + (c0 - 120));
            direct = true;
          }
        }
      } else {  // AMODE 0, fp32
        if (k0 < K) {
          const float* p = (const float*)Asrc + (size_t)row * K + k0;
          const float4 x0 = *reinterpret_cast<const float4*>(p);
          const float4 x1 = *reinterpret_cast<const float4*>(p + 4);
          sv[0] = (short)f2bf(x0.x); sv[1] = (short)f2bf(x0.y);
          sv[2] = (short)f2bf(x0.z); sv[3] = (short)f2bf(x0.w);
          sv[4] = (short)f2bf(x1.x); sv[5] = (short)f2bf(x1.y);
          sv[6] = (short)f2bf(x1.z); sv[7] = (short)f2bf(x1.w);
          direct = true;
        }
      }
      if (!direct) {
#pragma unroll
        for (int j = 0; j < 8; j++) sv[j] = 0;
      }
      *reinterpret_cast<short8*>(&Asm[(g * 64 + (tid & 63)) * 8]) = sv;
    }
    {
      const size_t wbase = ((size_t)blockIdx.x * KT + t) * 4096;
#pragma unroll
      for (int it = 0; it < 2; it++) {
        const int idx = it * 256 + tid;
        *reinterpret_cast<short8*>(&Bsm[idx * 8]) =
            *reinterpret_cast<const short8*>(WP + wbase + (size_t)idx * 8);
      }
    }
    __syncthreads();
    short8 af[4], bfr[4];
#pragma unroll
    for (int mi = 0; mi < 4; mi++)
      af[mi] = *reinterpret_cast<const short8*>(&Asm[((wr * 4 + mi) * 64 + l) * 8]);
#pragma unroll
    for (int ni = 0; ni < 4; ni++)
      bfr[ni] = *reinterpret_cast<const short8*>(&Bsm[((wc * 4 + ni) * 64 + l) * 8]);
#pragma unroll
    for (int mi = 0; mi < 4; mi++)
#pragma unroll
      for (int ni = 0; ni < 4; ni++)
        acc[mi][ni] = __builtin_amdgcn_mfma_f32_16x16x32_bf16(
            af[mi], bfr[ni], acc[mi][ni], 0, 0, 0);
    __syncthreads();
  }

#pragma unroll
  for (int mi = 0; mi < 4; mi++)
#pragma unroll
    for (int ni = 0; ni < 4; ni++) {
      const int col = col0 + wc * 64 + ni * 16 + (l & 15);
      if (col < Nout) {
        const float bbv = bias ? bias[col] : 0.f;
        const int rbase = row0 + wr * 64 + mi * 16 + ((l >> 4) << 2);
#pragma unroll
        for (int q = 0; q < 4; q++) {
          const int row = rbase + q;
          if (row < M) {
            float val = acc[mi][ni][q] + bbv;
            if (RELU) val = fmaxf(val, 0.f);
            if (OBF)
              ((unsigned short*)Cdst)[(size_t)row * Nout + col] = f2bf(val);
            else
              ((float*)Cdst)[(size_t)row * Nout + col] = val;
          }
        }
      }
    }
}

// ---------------------------------------------------------------------------
// Fused GGNN step: one block = 64 rows, FULL K=608 resident in LDS (77.8 KB,
// 2 blocks/CU). Sweeps all 7 col-tiles -> A fetched exactly once from HBM.
// B fragments read directly from packed WPF (L2-resident), double-buffered.
// Waves = 4 column strips (32 cols x 64 rows each) so each B fragment is
// loaded once per block. Single barrier; LDS read-only afterwards.
// Epilogue = fused GRU (gates interleaved col=4*ch+g).
// ---------------------------------------------------------------------------
__global__ __launch_bounds__(256) void ggnn_step_kernel(
    const unsigned short* __restrict__ s,    // [NN,400] bf16
    const unsigned short* __restrict__ hb,   // [NN,200] bf16 (current)
    const short* __restrict__ WPF,           // packed [7][19][8][64][8]
    const float* __restrict__ bbv,
    const float* __restrict__ tt0, const float* __restrict__ tt1,
    const float* __restrict__ cnt2,
    float* __restrict__ hout,                // [NN,200] fp32 carry (may be null)
    unsigned short* __restrict__ hbout)      // [NN,200] bf16 (next)
{
  __shared__ short Asm[38912];               // 19 tiles x (64 rows x 32 k)
  const int tid = threadIdx.x;
  const int row0 = blockIdx.x * 64;
  const int l = tid & 63;
  const int w = tid >> 6;

  // ---- stage A: 64 rows x 608 k (k<400: s; 400..599: hb; >=600: 0) ----
  {
    const int rr = l & 15;
    const int kg = l >> 4;
    const int row = row0 + w * 16 + rr;      // w doubles as row-group here
    const unsigned short* srow = s + (size_t)row * 400;
    const unsigned short* hrow = hb + (size_t)row * 200;
#pragma unroll
    for (int kt = 0; kt < 19; ++kt) {
      const int k0 = kt * 32 + kg * 8;
      short8 sv;
      if (k0 < 400) {
        sv = *reinterpret_cast<const short8*>(srow + k0);
      } else if (k0 < 600) {
        sv = *reinterpret_cast<const short8*>(hrow + (k0 - 400));
      } else {
#pragma unroll
        for (int j = 0; j < 8; j++) sv[j] = 0;
      }
      *reinterpret_cast<short8*>(&Asm[kt * 2048 + tid * 8]) = sv;
    }
  }
  __syncthreads();

  for (int ct = 0; ct < 7; ++ct) {
    f32x4 acc[4][2];
#pragma unroll
    for (int mi = 0; mi < 4; mi++) {
      acc[mi][0] = (f32x4){0.f, 0.f, 0.f, 0.f};
      acc[mi][1] = (f32x4){0.f, 0.f, 0.f, 0.f};
    }
    // B base for this wave's col strip (cg = w*2 + ni)
    const short* Bbase = WPF + (((size_t)ct * 19 * 8) + (size_t)w * 2) * 512 + (size_t)l * 8;
    short8 b0 = *reinterpret_cast<const short8*>(Bbase);
    short8 b1 = *reinterpret_cast<const short8*>(Bbase + 512);
    for (int kt = 0; kt < 19; ++kt) {
      const int ktn = (kt < 18) ? kt + 1 : 18;
      const short8 n0 = *reinterpret_cast<const short8*>(Bbase + (size_t)ktn * 4096);
      const short8 n1 = *reinterpret_cast<const short8*>(Bbase + (size_t)ktn * 4096 + 512);
      short8 af[4];
#pragma unroll
      for (int mi = 0; mi < 4; mi++)
        af[mi] = *reinterpret_cast<const short8*>(&Asm[kt * 2048 + (mi * 64 + l) * 8]);
#pragma unroll
      for (int mi = 0; mi < 4; mi++) {
        acc[mi][0] = __builtin_amdgcn_mfma_f32_16x16x32_bf16(af[mi], b0, acc[mi][0], 0, 0, 0);
        acc[mi][1] = __builtin_amdgcn_mfma_f32_16x16x32_bf16(af[mi], b1, acc[mi][1], 0, 0, 0);
      }
      b0 = n0; b1 = n1;
    }
    // ---- fused GRU epilogue for this col strip ----
    const int gq = l & 3;
#pragma unroll
    for (int mi = 0; mi < 4; ++mi) {
#pragma unroll
      for (int q = 0; q < 4; ++q) {
        const int row = row0 + mi * 16 + ((l >> 4) << 2) + q;
        const float2 cc = *reinterpret_cast<const float2*>(cnt2 + (size_t)row * 2);
#pragma unroll
        for (int ni = 0; ni < 2; ++ni) {
          const int col = ct * 128 + w * 32 + ni * 16 + (l & 15);
          float val = acc[mi][ni][q] + bbv[col] + cc.x * tt0[col] + cc.y * tt1[col];
          float av;
          if (gq == 0 || gq == 1) av = 1.f / (1.f + expf(-val));
          else av = val;
          const float x1 = __shfl_xor(av, 1);
          const float x2 = __shfl_xor(av, 2);
          const float x3 = __shfl_xor(av, 3);
          if (gq == 2 && col < 800) {
            const int ch = col >> 2;
            const float nv = tanhf(av + x2 * x1);
            float hold;
            if (hout) hold = hout[(size_t)row * 200 + ch];
            else hold = bf2f(hb[(size_t)row * 200 + ch]);
            const float hnew = (1.f - x3) * nv + x3 * hold;
            if (hout) hout[(size_t)row * 200 + ch] = hnew;
            hbout[(size_t)row * 200 + ch] = f2bf(hnew);
          }
        }
      }
    }
  }
}

// ---------------------------------------------------------------------------
__global__ void pack_w(const float* __restrict__ W, short* __restrict__ WP,
                       int Nout, int K, int Ntp, int Kp, int CIN) {
  const int KT = Kp >> 5;
  const int total = (Ntp >> 7) * KT * 512;
  const int u = blockIdx.x * 256 + threadIdx.x;
  if (u >= total) return;
  const int l = u & 63;
  const int g = (u >> 6) & 7;
  const int T = (u >> 9) % KT;
  const int ct = (u >> 9) / KT;
  const int n = ct * 128 + g * 16 + (l & 15);
  const int kb = T * 32 + ((l >> 4) << 3);
  short8 sv;
#pragma unroll
  for (int j = 0; j < 8; j++) {
    const int k = kb + j;
    float v = 0.f;
    if (n < Nout && k < K) {
      if (CIN > 0) {
        const int kw = k / CIN, i = k - kw * CIN;
        v = W[((size_t)n * CIN + i) * 3 + kw];
      } else {
        v = W[(size_t)n * K + k];
      }
    }
    sv[j] = (short)f2bf(v);
  }
  *reinterpret_cast<short8*>(&WP[(size_t)u * 8]) = sv;
}

// ---------------------------------------------------------------------------
__global__ void fill_kernel(float* __restrict__ p, int n, float v) {
  const int t = blockIdx.x * 256 + threadIdx.x;
  if (t < n) p[t] = v;
}

__global__ void pad_h_kernel(const float* __restrict__ x, float* __restrict__ h,
                             unsigned short* __restrict__ hb) {
  const int t = blockIdx.x * 256 + threadIdx.x;
  if (t >= NN * HH) return;
  const int n = t / HH, j = t - n * HH;
  const float v = (j < DD) ? x[(size_t)n * DD + j] : 0.0f;
  if (h) h[t] = v;
  hb[t] = f2bf(v);
}

// ---- CSR build ----
__global__ void hist_kernel(const int* __restrict__ ei, int* __restrict__ cnt) {
  const int e = blockIdx.x * 256 + threadIdx.x;
  if (e < EE) atomicAdd(&cnt[ei[EE + e]], 1);
}
__global__ void scan1_kernel(const int* __restrict__ cnt, int* __restrict__ ex,
                             int* __restrict__ bsum) {
  __shared__ int sm[256];
  const int tid = threadIdx.x;
  const int i = blockIdx.x * 256 + tid;
  const int v = cnt[i];
  sm[tid] = v; __syncthreads();
  for (int off = 1; off < 256; off <<= 1) {
    int t = (tid >= off) ? sm[tid - off] : 0;
    __syncthreads();
    sm[tid] += t;
    __syncthreads();
  }
  ex[i] = sm[tid] - v;
  if (tid == 255) bsum[blockIdx.x] = sm[255];
}
__global__ void scan2_kernel(int* __restrict__ bsum, int nb) {
  if (threadIdx.x == 0 && blockIdx.x == 0) {
    int run = 0;
    for (int b = 0; b < nb; b++) { int t = bsum[b]; bsum[b] = run; run += t; }
  }
}
__global__ void scan3_kernel(const int* __restrict__ ex, const int* __restrict__ bsum,
                             int* __restrict__ rowptr) {
  const int i = blockIdx.x * 256 + threadIdx.x;
  if (i < NN) rowptr[i] = ex[i] + bsum[i >> 8];
  if (i == 0) rowptr[NN] = EE;
}
__global__ void fillcsr_kernel(const int* __restrict__ ei, const int* __restrict__ et,
                               const int* __restrict__ rowptr, int* __restrict__ fcur,
                               int* __restrict__ eidx) {
  const int e = blockIdx.x * 256 + threadIdx.x;
  if (e >= EE) return;
  const int d = ei[EE + e];
  const int pos = atomicAdd(&fcur[d], 1);
  eidx[rowptr[d] + pos] = (ei[e] << 1) | (et[e] & 1);
}
__global__ void count_kernel(const int* __restrict__ ei, const int* __restrict__ et,
                             float* __restrict__ cnt2) {
  const int e = blockIdx.x * 256 + threadIdx.x;
  if (e >= EE) return;
  atomicAdd(&cnt2[(size_t)ei[EE + e] * 2 + (et[e] & 1)], 1.0f);
}

// ---- setup algebra kernels ----
__global__ void wcat2_kernel(const float* __restrict__ gw, float* __restrict__ W2) {
  const int t = blockIdx.x * 256 + threadIdx.x;
  if (t >= 400 * 200) return;
  const int m = t / 200, j = t - m * 200;
  const int ty = (m < 200) ? 0 : 1;
  const int kk = m - ty * 200;
  W2[t] = gw[(size_t)ty * 40000 + j * 200 + kk];
}
__global__ void ta_kernel(const float* __restrict__ wih, const float* __restrict__ gb,
                          float* __restrict__ ta) {
  const int o = blockIdx.x * 256 + threadIdx.x;
  if (o >= 1200) return;
  const int which = o / 600, oo = o - which * 600;
  float s = 0.f;
  for (int j = 0; j < 200; j++) s += wih[(size_t)oo * 200 + j] * gb[which * 200 + j];
  ta[o] = s;
}
__global__ void wfd_kernel(const float* __restrict__ M1, const float* __restrict__ whh,
                           float* __restrict__ WFD) {
  const int t = blockIdx.x * 256 + threadIdx.x;
  if (t >= 800 * 600) return;
  const int c = t / 600, k = t - c * 600;
  const int ch = c >> 2, g = c & 3;
  float v = 0.f;
  if (g == 0) v = (k < 400) ? M1[(size_t)ch * 400 + k] : whh[(size_t)ch * 200 + (k - 400)];
  else if (g == 1) v = (k < 400) ? M1[(size_t)(200 + ch) * 400 + k]
                                 : whh[(size_t)(200 + ch) * 200 + (k - 400)];
  else if (g == 2) v = (k < 400) ? M1[(size_t)(400 + ch) * 400 + k] : 0.f;
  else v = (k < 400) ? 0.f : whh[(size_t)(400 + ch) * 200 + (k - 400)];
  WFD[t] = v;
}
__global__ void bbtt_kernel(const float* __restrict__ bih, const float* __restrict__ bhh,
                            const float* __restrict__ ta, float* __restrict__ bb,
                            float* __restrict__ tt0, float* __restrict__ tt1) {
  const int c = blockIdx.x * 256 + threadIdx.x;
  if (c >= 896) return;
  const int ch = c >> 2, g = c & 3;
  float b = 0.f, t0 = 0.f, t1 = 0.f;
  if (ch < 200) {
    if (g == 0) b = bih[ch] + bhh[ch];
    else if (g == 1) b = bih[200 + ch] + bhh[200 + ch];
    else if (g == 2) b = bih[400 + ch];
    else b = bhh[400 + ch];
    if (g < 3) { t0 = ta[g * 200 + ch]; t1 = ta[600 + g * 200 + ch]; }
  }
  bb[c] = b; tt0[c] = t0; tt1[c] = t1;
}

// ---- CSR gather-sum ----
__global__ void gather_kernel(const unsigned short* __restrict__ hb,
                              const int* __restrict__ rowptr,
                              const int* __restrict__ eidx,
                              unsigned short* __restrict__ s) {
  const int nid = blockIdx.x * 4 + (threadIdx.x >> 6);
  const int l = threadIdx.x & 63;
  if (nid >= NN) return;
  const int beg = rowptr[nid], end = rowptr[nid + 1];
  float a00 = 0, a01 = 0, a10 = 0, a11 = 0;
  float b00 = 0, b01 = 0, b10 = 0, b11 = 0;
  const unsigned int* H32 = (const unsigned int*)hb;
  for (int e = beg; e < end; e++) {
    const int pe = eidx[e];
    const int src = pe >> 1, ty = pe & 1;
    const unsigned int* hr = H32 + (size_t)src * 100;
    const unsigned int u0 = hr[l];
    unsigned int u1 = 0;
    if (l < 36) u1 = hr[64 + l];
    const float f0 = bf2f((unsigned short)(u0 & 0xffffu));
    const float f1 = bf2f((unsigned short)(u0 >> 16));
    const float f2 = bf2f((unsigned short)(u1 & 0xffffu));
    const float f3 = bf2f((unsigned short)(u1 >> 16));
    if (ty == 0) { a00 += f0; a01 += f1; a10 += f2; a11 += f3; }
    else         { b00 += f0; b01 += f1; b10 += f2; b11 += f3; }
  }
  unsigned int* S32 = (unsigned int*)s;
  const size_t rb = (size_t)nid * 200;
  S32[rb + l] = (unsigned int)f2bf(a00) | ((unsigned int)f2bf(a01) << 16);
  S32[rb + 100 + l] = (unsigned int)f2bf(b00) | ((unsigned int)f2bf(b01) << 16);
  if (l < 36) {
    S32[rb + 64 + l] = (unsigned int)f2bf(a10) | ((unsigned int)f2bf(a11) << 16);
    S32[rb + 164 + l] = (unsigned int)f2bf(b10) | ((unsigned int)f2bf(b11) << 16);
  }
}

// ---- readout helpers ----
__global__ void pool_kernel(const float* __restrict__ src, float* __restrict__ dst,
                            int nb, int Lin, int Lout, int C, int win) {
  const size_t t = (size_t)blockIdx.x * 256 + threadIdx.x;
  const size_t tot = (size_t)nb * Lout * C;
  if (t >= tot) return;
  const int c = (int)(t % C);
  const size_t bp = t / C;
  const int p = (int)(bp % Lout);
  const int b = (int)(bp / Lout);
  const float* s0 = src + ((size_t)b * Lin + 2 * p) * C + c;
  float v = s0[0];
  for (int q = 1; q < win; q++) v = fmaxf(v, s0[(size_t)q * C]);
  dst[t] = v;
}

__global__ void prodmean_kernel(const float* __restrict__ y, const float* __restrict__ z,
                                float* __restrict__ avg, int g0, int nb) {
  const int t = blockIdx.x * 256 + threadIdx.x;
  if (t >= nb * 256) return;
  const int b = t >> 8, j = t & 255;
  const float* yr = y + (size_t)b * 99 * 256 + j;
  const float* zr = z + (size_t)b * 99 * 256 + j;
  float sum = 0.0f;
  for (int p = 0; p < 99; p++) sum += yr[(size_t)p * 256] * zr[(size_t)p * 256];
  avg[(size_t)(g0 + b) * 256 + j] = sum * (1.0f / 99.0f);
}

// ---------------------------------------------------------------------------
extern "C" void kernel_launch(void* const* d_in, const int* in_sizes, int n_in,
                              void* d_out, int out_size, void* d_ws, size_t ws_size,
                              hipStream_t stream) {
  const float* x       = (const float*)d_in[0];
  const int*   ei      = (const int*)d_in[1];
  const int*   et      = (const int*)d_in[2];
  const float* ggnn_W  = (const float*)d_in[3];
  const float* ggnn_b  = (const float*)d_in[4];
  const float* gru_Wih = (const float*)d_in[5];
  const float* gru_Whh = (const float*)d_in[6];
  const float* gru_bih = (const float*)d_in[7];
  const float* gru_bhh = (const float*)d_in[8];
  const float* conv1_w = (const float*)d_in[9];
  const float* conv1_b = (const float*)d_in[10];
  const float* conv2_w = (const float*)d_in[11];
  const float* conv2_b = (const float*)d_in[12];
  const float* cconv1_w = (const float*)d_in[13];
  const float* cconv1_b = (const float*)d_in[14];
  const float* cconv2_w = (const float*)d_in[15];
  const float* cconv2_b = (const float*)d_in[16];
  const float* mlp_y_w = (const float*)d_in[17];
  const float* mlp_y_b = (const float*)d_in[18];
  const float* mlp_z_w = (const float*)d_in[19];
  const float* mlp_z_b = (const float*)d_in[20];
  const float* ml_l1_w = (const float*)d_in[21];
  const float* ml_l1_b = (const float*)d_in[22];
  const float* ml_f1_w = (const float*)d_in[23];
  const float* ml_f1_b = (const float*)d_in[24];
  const float* ml_f2_w = (const float*)d_in[25];
  const float* ml_f2_b = (const float*)d_in[26];
  const float* cls_w   = (const float*)d_in[27];
  const float* cls_b   = (const float*)d_in[28];
  float* out = (float*)d_out;

  // ---------------- workspace layout (bytes) ----------------
  char* base = (char*)d_ws;
  size_t off = 0;
  auto alloc = [&](size_t bytes) { char* p = base + off; off += (bytes + 15) & ~(size_t)15; return p; };
  unsigned short* s   = (unsigned short*)alloc(81920000);  // [NN,400] bf16
  unsigned short* hb1 = (unsigned short*)alloc(40960000);  // mirror buf (odd)
  unsigned short* hb0 = (unsigned short*)alloc(40960000);  // mirror buf (even/final)
  int* eidx    = (int*)alloc(3276800);
  int* rowptr  = (int*)alloc(409604);
  float* cnt2  = (float*)alloc(819200);
  short* WPF   = (short*)alloc(1089536);
  short* WPwc  = (short*)alloc(229376);
  short* WPc1  = (short*)alloc(311296);
  short* WPcc1 = (short*)alloc(737280);
  short* WPc2  = (short*)alloc(114688);
  short* WPcc2 = (short*)alloc(245760);
  short* WPmy  = (short*)alloc(114688);
  short* WPmz  = (short*)alloc(163840);
  short* WPl1  = (short*)alloc(65536);
  short* WPf1  = (short*)alloc(32768);
  short* WPf2  = (short*)alloc(16384);
  short* WPcls = (short*)alloc(32768);
  float* bb  = (float*)alloc(3584);
  float* tt0 = (float*)alloc(3584);
  float* tt1 = (float*)alloc(3584);
  float* avg = (float*)alloc(262144);
  float* h1b = (float*)alloc(131072);
  float* hf1 = (float*)alloc(65536);
  const size_t persist = off;
  float* h = (float*)alloc(81920000);          // optional fp32 GRU carry
  const bool has_h = (ws_size >= off);

  const int fill_blocks = (out_size + 255) / 256;
  if (ws_size < persist) {
    fill_kernel<<<fill_blocks, 256, 0, stream>>>(out, out_size,
                                                 -(float)(ws_size >> 20));
    return;
  }
  float* hptr = has_h ? h : nullptr;

  // setup-only scratch aliased into s (dead before first gather)
  char* ali = (char*)s;
  float* Wcat2 = (float*)(ali);            // 320,000
  float* M1f   = (float*)(ali + 320000);   // 960,000
  float* WFD   = (float*)(ali + 1280000);  // 1,920,000
  float* ta    = (float*)(ali + 3200000);  // 4,800
  int* cnt     = (int*)(ali + 3204800);    // 409,600
  int* ex      = (int*)(ali + 3614400);    // 409,600
  int* bsum    = (int*)(ali + 4024000);    // 1,600
  int* fcur    = (int*)(ali + 4025600);    // 409,600

  fill_kernel<<<fill_blocks, 256, 0, stream>>>(out, out_size, 1.0e4f);

  // ---- setup ----
  pad_h_kernel<<<80000, 256, 0, stream>>>(x, hptr, hb0);
  hipMemsetAsync(cnt, 0, 409600, stream);
  hipMemsetAsync(fcur, 0, 409600, stream);
  hipMemsetAsync(cnt2, 0, 819200, stream);
  hist_kernel<<<3200, 256, 0, stream>>>(ei, cnt);
  scan1_kernel<<<400, 256, 0, stream>>>(cnt, ex, bsum);
  scan2_kernel<<<1, 64, 0, stream>>>(bsum, 400);
  scan3_kernel<<<400, 256, 0, stream>>>(ex, bsum, rowptr);
  fillcsr_kernel<<<3200, 256, 0, stream>>>(ei, et, rowptr, fcur, eidx);
  count_kernel<<<3200, 256, 0, stream>>>(ei, et, cnt2);

  auto packs = [&](const float* W, short* WP, int Nout, int K, int Ntp, int Kp, int CIN) {
    const int total = (Ntp >> 7) * (Kp >> 5) * 512;
    pack_w<<<(total + 255) / 256, 256, 0, stream>>>(W, WP, Nout, K, Ntp, Kp, CIN);
  };
  // M1 = Wih @ Wcat2^T  (600 x 400)
  wcat2_kernel<<<313, 256, 0, stream>>>(ggnn_W, Wcat2);
  packs(Wcat2, WPwc, 400, 200, 512, 224, 0);
  gemm_mfma<0, 0, 0, 0, 0><<<dim3(4, 5), 256, 0, stream>>>(
      gru_Wih, nullptr, WPwc, nullptr, M1f, 600, 400, 200, 7,
      nullptr, nullptr, nullptr, nullptr, nullptr);
  ta_kernel<<<5, 256, 0, stream>>>(gru_Wih, ggnn_b, ta);
  wfd_kernel<<<1875, 256, 0, stream>>>(M1f, gru_Whh, WFD);
  packs(WFD, WPF, 800, 600, 896, 608, 0);
  bbtt_kernel<<<4, 256, 0, stream>>>(gru_bih, gru_bhh, ta, bb, tt0, tt1);
  packs(conv1_w, WPc1,  200, 600, 256, 608, 200);
  packs(cconv1_w,WPcc1, 320, 960, 384, 960, 320);
  packs(conv2_w, WPc2,  200, 200, 256, 224, 0);
  packs(cconv2_w,WPcc2, 320, 320, 384, 320, 0);
  packs(mlp_y_w, WPmy,  256, 200, 256, 224, 0);
  packs(mlp_z_w, WPmz,  256, 320, 256, 320, 0);
  packs(ml_l1_w, WPl1,  128, 256, 128, 256, 0);
  packs(ml_f1_w, WPf1,   64, 128, 128, 128, 0);
  packs(ml_f2_w, WPf2,  128,  64, 128,  64, 0);
  packs(cls_w,   WPcls,   2, 128, 128, 128, 0);

  // ---- GGNN: 8 steps, 2 kernels each ----
  unsigned short* hbb[2] = {hb0, hb1};
  for (int step = 0; step < NSTEPS; step++) {
    unsigned short* hcur = hbb[step & 1];
    unsigned short* hnxt = hbb[(step & 1) ^ 1];
    gather_kernel<<<25600, 256, 0, stream>>>(hcur, rowptr, eidx, s);
    ggnn_step_kernel<<<1600, 256, 0, stream>>>(
        s, hcur, WPF, bb, tt0, tt1, cnt2, hptr, hnxt);
  }
  // final mirror is hb0 (after 8 steps)

  // ---- conv/pool/mlp readout, G=64 graphs per chunk (arena = s+hb1) ----
  const int G = 64;
  float* b0  = (float*)s;                          // G*398*320 fp32
  float* b1  = b0 + (size_t)G * 127360;            // G*198*320
  float* b2  = b1 + (size_t)G * 63360;             // G*198*320
  float* y2c = b2 + (size_t)G * 63360;             // G*99*200
  float* z2c = y2c + (size_t)G * 19800;            // G*99*320

  for (int g0 = 0; g0 < BB; g0 += G) {
    const unsigned short* hc = hb0 + (size_t)g0 * LL * HH;
    const float* xc = x + (size_t)g0 * LL * DD;
    const int M1 = G * 398, M2 = G * 198, M3 = G * 99;
    const int gy1 = (M1 + 127) / 128, gy2 = (M2 + 127) / 128, gy3 = (M3 + 127) / 128;
    gemm_mfma<1, 1, 0, 1, 0><<<dim3(2, gy1), 256, 0, stream>>>(
        hc, nullptr, WPc1, conv1_b, b0, M1, 200, 600, 19,
        nullptr, nullptr, nullptr, nullptr, nullptr);
    pool_kernel<<<(int)(((size_t)G * 198 * 200 + 255) / 256), 256, 0, stream>>>(
        b0, b1, G, 398, 198, 200, 3);
    gemm_mfma<0, 0, 0, 1, 0><<<dim3(2, gy2), 256, 0, stream>>>(
        b1, nullptr, WPc2, conv2_b, b2, M2, 200, 200, 7,
        nullptr, nullptr, nullptr, nullptr, nullptr);
    pool_kernel<<<(int)(((size_t)G * 99 * 200 + 255) / 256), 256, 0, stream>>>(
        b2, y2c, G, 198, 99, 200, 2);
    gemm_mfma<2, 1, 0, 1, 0><<<dim3(3, gy1), 256, 0, stream>>>(
        hc, xc, WPcc1, cconv1_b, b0, M1, 320, 960, 30,
        nullptr, nullptr, nullptr, nullptr, nullptr);
    pool_kernel<<<(int)(((size_t)G * 198 * 320 + 255) / 256), 256, 0, stream>>>(
        b0, b1, G, 398, 198, 320, 3);
    gemm_mfma<0, 0, 0, 1, 0><<<dim3(3, gy2), 256, 0, stream>>>(
        b1, nullptr, WPcc2, cconv2_b, b2, M2, 320, 320, 10,
        nullptr, nullptr, nullptr, nullptr, nullptr);
    pool_kernel<<<(int)(((size_t)G * 99 * 320 + 255) / 256), 256, 0, stream>>>(
        b2, z2c, G, 198, 99, 320, 2);
    gemm_mfma<0, 0, 0, 0, 0><<<dim3(2, gy3), 256, 0, stream>>>(
        y2c, nullptr, WPmy, mlp_y_b, b0, M3, 256, 200, 7,
        nullptr, nullptr, nullptr, nullptr, nullptr);
    gemm_mfma<0, 0, 0, 0, 0><<<dim3(2, gy3), 256, 0, stream>>>(
        z2c, nullptr, WPmz, mlp_z_b, b1, M3, 256, 320, 10,
        nullptr, nullptr, nullptr, nullptr, nullptr);
    prodmean_kernel<<<(G * 256 + 255) / 256, 256, 0, stream>>>(b0, b1, avg, g0, G);
  }

  // ---- head ----
  gemm_mfma<0, 0, 0, 1, 0><<<dim3(1, 2), 256, 0, stream>>>(
      avg, nullptr, WPl1, ml_l1_b, h1b, 256, 128, 256, 8,
      nullptr, nullptr, nullptr, nullptr, nullptr);
  gemm_mfma<0, 0, 0, 1, 0><<<dim3(1, 2), 256, 0, stream>>>(
      h1b, nullptr, WPf1, ml_f1_b, hf1, 256, 64, 128, 4,
      nullptr, nullptr, nullptr, nullptr, nullptr);
  gemm_mfma<0, 0, 0, 1, 0><<<dim3(1, 2), 256, 0, stream>>>(
      hf1, nullptr, WPf2, ml_f2_b, out + 512, 256, 128, 64, 2,
      nullptr, nullptr, nullptr, nullptr, nullptr);
  gemm_mfma<0, 0, 0, 0, 0><<<dim3(1, 2), 256, 0, stream>>>(
      out + 512, nullptr, WPcls, cls_b, out, 256, 2, 128, 4,
      nullptr, nullptr, nullptr, nullptr, nullptr);
}

// Round 7
// 6519.661 us; speedup vs baseline: 1.4541x; 1.4541x over previous
//
#include <hip/hip_runtime.h>
#include <hip/hip_bf16.h>
#include <cstdint>
#include <cstddef>

static constexpr int NN = 102400;   // nodes
static constexpr int EE = 819200;   // edges
static constexpr int DD = 120;      // input channels
static constexpr int HH = 200;      // hidden
static constexpr int LL = 400;      // nodes per graph
static constexpr int BB = 256;      // graphs
static constexpr int NSTEPS = 8;

typedef __attribute__((ext_vector_type(8))) short short8;
typedef __attribute__((ext_vector_type(4))) float f32x4;

__device__ __forceinline__ unsigned short f2bf(float f) {
  union { float f; unsigned u; } v; v.f = f;
  return (unsigned short)((v.u + 0x7fffu + ((v.u >> 16) & 1u)) >> 16);
}
__device__ __forceinline__ float bf2f(unsigned short s) {
  union { unsigned u; float f; } v; v.u = ((unsigned)s) << 16; return v.f;
}

// ---------------------------------------------------------------------------
// MFMA GEMM: C[M,Nout] = op(A)[M,K] @ W[Nout,K]^T + bias (+relu)
// 128x128 tile, 4 waves, BK=32, mfma_f32_16x16x32_bf16.
// LDS layout: per 16-row group g (8 groups): 64 lane-slots x 16B.
// WP pre-packed in the same fragment-major layout: [ct][t][g][l][8].
// AMODE 0: A row-major [M,K]; ASRC 0=fp32, 1=bf16
// AMODE 1: conv1 im2col over bf16 hb chunk (K=600)
// AMODE 2: cconv1 im2col concat(x fp32, hb bf16) (K=960)
// AMODE 3: GGNN fused: k<400 -> s[row*400+k], 400<=k<600 -> hb[row*200+k-400]
// EPI 0: normal store (OBF/RELU). EPI 2: fused GRU epilogue (4-gate
//        interleaved cols: col=4*ch+gate, gates r,z,inn,hn).
// ---------------------------------------------------------------------------
template<int AMODE, int ASRC, int OBF, int RELU, int EPI>
__global__ __launch_bounds__(256) void gemm_mfma(
    const void* __restrict__ Asrc, const void* __restrict__ A2,
    const short* __restrict__ WP, const float* __restrict__ bias,
    void* __restrict__ Cdst, int M, int Nout, int K, int KT,
    const float* __restrict__ tt0, const float* __restrict__ tt1,
    const float* __restrict__ cnt2, float* __restrict__ hout,
    unsigned short* __restrict__ hbout)
{
  __shared__ short Asm[4096];
  __shared__ short Bsm[4096];
  const int tid = threadIdx.x;
  const int row0 = blockIdx.y * 128;
  const int col0 = blockIdx.x * 128;

  f32x4 acc[4][4];
#pragma unroll
  for (int mi = 0; mi < 4; mi++)
#pragma unroll
    for (int ni = 0; ni < 4; ni++) acc[mi][ni] = (f32x4){0.f, 0.f, 0.f, 0.f};

  const int r = tid & 15;
  const int kgl = (tid >> 4) & 3;
  const int ghalf = tid >> 6;
  const int w = tid >> 6, l = tid & 63;
  const int wr = w >> 1, wc = w & 1;

  for (int t = 0; t < KT; t++) {
#pragma unroll
    for (int half = 0; half < 2; half++) {
      const int g = ghalf + half * 4;
      int row = row0 + g * 16 + r;
      if (row >= M) row = M - 1;
      const int k0 = t * 32 + kgl * 8;
      short8 sv;
      bool direct = false;
      if (AMODE == 0 && ASRC == 1) {
        if (k0 < K) {
          sv = *reinterpret_cast<const short8*>(
              (const unsigned short*)Asrc + (size_t)row * K + k0);
          direct = true;
        }
      } else if (AMODE == 1) {
        if (k0 < K) {
          const int b = row / 398, tt = row - b * 398;
          const int tap = k0 / 200, i0 = k0 - tap * 200;
          sv = *reinterpret_cast<const short8*>(
              (const unsigned short*)Asrc + ((size_t)(b * 400 + tt + tap)) * 200 + i0);
          direct = true;
        }
      } else if (AMODE == 3) {
        if (k0 < 400) {
          sv = *reinterpret_cast<const short8*>(
              (const unsigned short*)Asrc + (size_t)row * 400 + k0);
          direct = true;
        } else if (k0 < 600) {
          sv = *reinterpret_cast<const short8*>(
              (const unsigned short*)A2 + (size_t)row * 200 + (k0 - 400));
          direct = true;
        }
      } else if (AMODE == 2) {
        if (k0 < K) {
          const int b = row / 398, tt = row - b * 398;
          const int tap = k0 / 320, c0 = k0 - tap * 320;
          const int node = b * 400 + tt + tap;
          if (c0 < 120) {
            const float* p = (const float*)A2 + (size_t)node * 120 + c0;
            const float4 x0 = *reinterpret_cast<const float4*>(p);
            const float4 x1 = *reinterpret_cast<const float4*>(p + 4);
            sv[0] = (short)f2bf(x0.x); sv[1] = (short)f2bf(x0.y);
            sv[2] = (short)f2bf(x0.z); sv[3] = (short)f2bf(x0.w);
            sv[4] = (short)f2bf(x1.x); sv[5] = (short)f2bf(x1.y);
            sv[6] = (short)f2bf(x1.z); sv[7] = (short)f2bf(x1.w);
            direct = true;
          } else {
            sv = *reinterpret_cast<const short8*>(
                (const unsigned short*)Asrc + (size_t)node * 200 + (c0 - 120));
            direct = true;
          }
        }
      } else {  // AMODE 0, fp32
        if (k0 < K) {
          const float* p = (const float*)Asrc + (size_t)row * K + k0;
          const float4 x0 = *reinterpret_cast<const float4*>(p);
          const float4 x1 = *reinterpret_cast<const float4*>(p + 4);
          sv[0] = (short)f2bf(x0.x); sv[1] = (short)f2bf(x0.y);
          sv[2] = (short)f2bf(x0.z); sv[3] = (short)f2bf(x0.w);
          sv[4] = (short)f2bf(x1.x); sv[5] = (short)f2bf(x1.y);
          sv[6] = (short)f2bf(x1.z); sv[7] = (short)f2bf(x1.w);
          direct = true;
        }
      }
      if (!direct) {
#pragma unroll
        for (int j = 0; j < 8; j++) sv[j] = 0;
      }
      *reinterpret_cast<short8*>(&Asm[(g * 64 + (tid & 63)) * 8]) = sv;
    }
    {
      const size_t wbase = ((size_t)blockIdx.x * KT + t) * 4096;
#pragma unroll
      for (int it = 0; it < 2; it++) {
        const int idx = it * 256 + tid;
        *reinterpret_cast<short8*>(&Bsm[idx * 8]) =
            *reinterpret_cast<const short8*>(WP + wbase + (size_t)idx * 8);
      }
    }
    __syncthreads();
    short8 af[4], bfr[4];
#pragma unroll
    for (int mi = 0; mi < 4; mi++)
      af[mi] = *reinterpret_cast<const short8*>(&Asm[((wr * 4 + mi) * 64 + l) * 8]);
#pragma unroll
    for (int ni = 0; ni < 4; ni++)
      bfr[ni] = *reinterpret_cast<const short8*>(&Bsm[((wc * 4 + ni) * 64 + l) * 8]);
#pragma unroll
    for (int mi = 0; mi < 4; mi++)
#pragma unroll
      for (int ni = 0; ni < 4; ni++)
        acc[mi][ni] = __builtin_amdgcn_mfma_f32_16x16x32_bf16(
            af[mi], bfr[ni], acc[mi][ni], 0, 0, 0);
    __syncthreads();
  }

  if (EPI == 0) {
#pragma unroll
    for (int mi = 0; mi < 4; mi++)
#pragma unroll
      for (int ni = 0; ni < 4; ni++) {
        const int col = col0 + wc * 64 + ni * 16 + (l & 15);
        if (col < Nout) {
          const float bbv = bias ? bias[col] : 0.f;
          const int rbase = row0 + wr * 64 + mi * 16 + ((l >> 4) << 2);
#pragma unroll
          for (int q = 0; q < 4; q++) {
            const int row = rbase + q;
            if (row < M) {
              float val = acc[mi][ni][q] + bbv;
              if (RELU) val = fmaxf(val, 0.f);
              if (OBF)
                ((unsigned short*)Cdst)[(size_t)row * Nout + col] = f2bf(val);
              else
                ((float*)Cdst)[(size_t)row * Nout + col] = val;
            }
          }
        }
      }
  } else {
    // ---- fused GRU epilogue: cols are 4*ch+gate (r,z,inn,hn) ----
    const int g = l & 3;
#pragma unroll
    for (int mi = 0; mi < 4; mi++) {
#pragma unroll
      for (int q = 0; q < 4; q++) {
        const int row = row0 + wr * 64 + mi * 16 + ((l >> 4) << 2) + q;
        const float2 cc = *reinterpret_cast<const float2*>(cnt2 + (size_t)row * 2);
#pragma unroll
        for (int ni = 0; ni < 4; ni++) {
          const int col = col0 + wc * 64 + ni * 16 + (l & 15);
          float val = acc[mi][ni][q] + bias[col] + cc.x * tt0[col] + cc.y * tt1[col];
          float av;
          if (g == 0 || g == 1) av = 1.f / (1.f + expf(-val));
          else av = val;
          const float x1 = __shfl_xor(av, 1);   // for g2: hn (from g3)
          const float x2 = __shfl_xor(av, 2);   // for g2: r  (from g0)
          const float x3 = __shfl_xor(av, 3);   // for g2: z  (from g1)
          if (g == 2 && col < 800) {
            const int ch = col >> 2;
            const float nv = tanhf(av + x2 * x1);
            float hold;
            if (hout) hold = hout[(size_t)row * 200 + ch];
            else hold = bf2f(((const unsigned short*)A2)[(size_t)row * 200 + ch]);
            const float hnew = (1.f - x3) * nv + x3 * hold;
            if (hout) hout[(size_t)row * 200 + ch] = hnew;
            hbout[(size_t)row * 200 + ch] = f2bf(hnew);
          }
        }
      }
    }
  }
}

// ---------------------------------------------------------------------------
// Pack weights W[Nout,K] fp32 (or conv3 layout [Nout,CIN,3]) into the
// fragment-major bf16 layout.
__global__ void pack_w(const float* __restrict__ W, short* __restrict__ WP,
                       int Nout, int K, int Ntp, int Kp, int CIN) {
  const int KT = Kp >> 5;
  const int total = (Ntp >> 7) * KT * 512;
  const int u = blockIdx.x * 256 + threadIdx.x;
  if (u >= total) return;
  const int l = u & 63;
  const int g = (u >> 6) & 7;
  const int T = (u >> 9) % KT;
  const int ct = (u >> 9) / KT;
  const int n = ct * 128 + g * 16 + (l & 15);
  const int kb = T * 32 + ((l >> 4) << 3);
  short8 sv;
#pragma unroll
  for (int j = 0; j < 8; j++) {
    const int k = kb + j;
    float v = 0.f;
    if (n < Nout && k < K) {
      if (CIN > 0) {
        const int kw = k / CIN, i = k - kw * CIN;
        v = W[((size_t)n * CIN + i) * 3 + kw];
      } else {
        v = W[(size_t)n * K + k];
      }
    }
    sv[j] = (short)f2bf(v);
  }
  *reinterpret_cast<short8*>(&WP[(size_t)u * 8]) = sv;
}

// ---------------------------------------------------------------------------
__global__ void fill_kernel(float* __restrict__ p, int n, float v) {
  const int t = blockIdx.x * 256 + threadIdx.x;
  if (t < n) p[t] = v;
}

__global__ void pad_h_kernel(const float* __restrict__ x, float* __restrict__ h,
                             unsigned short* __restrict__ hb) {
  const int t = blockIdx.x * 256 + threadIdx.x;
  if (t >= NN * HH) return;
  const int n = t / HH, j = t - n * HH;
  const float v = (j < DD) ? x[(size_t)n * DD + j] : 0.0f;
  if (h) h[t] = v;
  hb[t] = f2bf(v);
}

// ---- CSR build ----
__global__ void hist_kernel(const int* __restrict__ ei, int* __restrict__ cnt) {
  const int e = blockIdx.x * 256 + threadIdx.x;
  if (e < EE) atomicAdd(&cnt[ei[EE + e]], 1);
}
__global__ void scan1_kernel(const int* __restrict__ cnt, int* __restrict__ ex,
                             int* __restrict__ bsum) {
  __shared__ int sm[256];
  const int tid = threadIdx.x;
  const int i = blockIdx.x * 256 + tid;
  const int v = cnt[i];
  sm[tid] = v; __syncthreads();
  for (int off = 1; off < 256; off <<= 1) {
    int t = (tid >= off) ? sm[tid - off] : 0;
    __syncthreads();
    sm[tid] += t;
    __syncthreads();
  }
  ex[i] = sm[tid] - v;
  if (tid == 255) bsum[blockIdx.x] = sm[255];
}
__global__ void scan2_kernel(int* __restrict__ bsum, int nb) {
  if (threadIdx.x == 0 && blockIdx.x == 0) {
    int run = 0;
    for (int b = 0; b < nb; b++) { int t = bsum[b]; bsum[b] = run; run += t; }
  }
}
__global__ void scan3_kernel(const int* __restrict__ ex, const int* __restrict__ bsum,
                             int* __restrict__ rowptr) {
  const int i = blockIdx.x * 256 + threadIdx.x;
  if (i < NN) rowptr[i] = ex[i] + bsum[i >> 8];
  if (i == 0) rowptr[NN] = EE;
}
__global__ void fillcsr_kernel(const int* __restrict__ ei, const int* __restrict__ et,
                               const int* __restrict__ rowptr, int* __restrict__ fcur,
                               int* __restrict__ eidx) {
  const int e = blockIdx.x * 256 + threadIdx.x;
  if (e >= EE) return;
  const int d = ei[EE + e];
  const int pos = atomicAdd(&fcur[d], 1);
  eidx[rowptr[d] + pos] = (ei[e] << 1) | (et[e] & 1);
}
__global__ void count_kernel(const int* __restrict__ ei, const int* __restrict__ et,
                             float* __restrict__ cnt2) {
  const int e = blockIdx.x * 256 + threadIdx.x;
  if (e >= EE) return;
  atomicAdd(&cnt2[(size_t)ei[EE + e] * 2 + (et[e] & 1)], 1.0f);
}

// ---- setup algebra kernels ----
__global__ void wcat2_kernel(const float* __restrict__ gw, float* __restrict__ W2) {
  const int t = blockIdx.x * 256 + threadIdx.x;
  if (t >= 400 * 200) return;
  const int m = t / 200, j = t - m * 200;
  const int ty = (m < 200) ? 0 : 1;
  const int kk = m - ty * 200;
  W2[t] = gw[(size_t)ty * 40000 + j * 200 + kk];
}
__global__ void ta_kernel(const float* __restrict__ wih, const float* __restrict__ gb,
                          float* __restrict__ ta) {
  const int o = blockIdx.x * 256 + threadIdx.x;
  if (o >= 1200) return;
  const int which = o / 600, oo = o - which * 600;
  float s = 0.f;
  for (int j = 0; j < 200; j++) s += wih[(size_t)oo * 200 + j] * gb[which * 200 + j];
  ta[o] = s;
}
__global__ void wfd_kernel(const float* __restrict__ M1, const float* __restrict__ whh,
                           float* __restrict__ WFD) {
  const int t = blockIdx.x * 256 + threadIdx.x;
  if (t >= 800 * 600) return;
  const int c = t / 600, k = t - c * 600;
  const int ch = c >> 2, g = c & 3;
  float v = 0.f;
  if (g == 0) v = (k < 400) ? M1[(size_t)ch * 400 + k] : whh[(size_t)ch * 200 + (k - 400)];
  else if (g == 1) v = (k < 400) ? M1[(size_t)(200 + ch) * 400 + k]
                                 : whh[(size_t)(200 + ch) * 200 + (k - 400)];
  else if (g == 2) v = (k < 400) ? M1[(size_t)(400 + ch) * 400 + k] : 0.f;
  else v = (k < 400) ? 0.f : whh[(size_t)(400 + ch) * 200 + (k - 400)];
  WFD[t] = v;
}
__global__ void bbtt_kernel(const float* __restrict__ bih, const float* __restrict__ bhh,
                            const float* __restrict__ ta, float* __restrict__ bb,
                            float* __restrict__ tt0, float* __restrict__ tt1) {
  const int c = blockIdx.x * 256 + threadIdx.x;
  if (c >= 896) return;
  const int ch = c >> 2, g = c & 3;
  float b = 0.f, t0 = 0.f, t1 = 0.f;
  if (ch < 200) {
    if (g == 0) b = bih[ch] + bhh[ch];
    else if (g == 1) b = bih[200 + ch] + bhh[200 + ch];
    else if (g == 2) b = bih[400 + ch];
    else b = bhh[400 + ch];
    if (g < 3) { t0 = ta[g * 200 + ch]; t1 = ta[600 + g * 200 + ch]; }
  }
  bb[c] = b; tt0[c] = t0; tt1[c] = t1;
}

// ---- CSR gather-sum ----
__global__ void gather_kernel(const unsigned short* __restrict__ hb,
                              const int* __restrict__ rowptr,
                              const int* __restrict__ eidx,
                              unsigned short* __restrict__ s) {
  const int nid = blockIdx.x * 4 + (threadIdx.x >> 6);
  const int l = threadIdx.x & 63;
  if (nid >= NN) return;
  const int beg = rowptr[nid], end = rowptr[nid + 1];
  float a00 = 0, a01 = 0, a10 = 0, a11 = 0;
  float b00 = 0, b01 = 0, b10 = 0, b11 = 0;
  const unsigned int* H32 = (const unsigned int*)hb;
  for (int e = beg; e < end; e++) {
    const int pe = eidx[e];
    const int src = pe >> 1, ty = pe & 1;
    const unsigned int* hr = H32 + (size_t)src * 100;
    const unsigned int u0 = hr[l];
    unsigned int u1 = 0;
    if (l < 36) u1 = hr[64 + l];
    const float f0 = bf2f((unsigned short)(u0 & 0xffffu));
    const float f1 = bf2f((unsigned short)(u0 >> 16));
    const float f2 = bf2f((unsigned short)(u1 & 0xffffu));
    const float f3 = bf2f((unsigned short)(u1 >> 16));
    if (ty == 0) { a00 += f0; a01 += f1; a10 += f2; a11 += f3; }
    else         { b00 += f0; b01 += f1; b10 += f2; b11 += f3; }
  }
  unsigned int* S32 = (unsigned int*)s;
  const size_t rb = (size_t)nid * 200;
  S32[rb + l] = (unsigned int)f2bf(a00) | ((unsigned int)f2bf(a01) << 16);
  S32[rb + 100 + l] = (unsigned int)f2bf(b00) | ((unsigned int)f2bf(b01) << 16);
  if (l < 36) {
    S32[rb + 64 + l] = (unsigned int)f2bf(a10) | ((unsigned int)f2bf(a11) << 16);
    S32[rb + 164 + l] = (unsigned int)f2bf(b10) | ((unsigned int)f2bf(b11) << 16);
  }
}

// ---- readout helpers ----
__global__ void pool_kernel(const float* __restrict__ src, float* __restrict__ dst,
                            int nb, int Lin, int Lout, int C, int win) {
  const size_t t = (size_t)blockIdx.x * 256 + threadIdx.x;
  const size_t tot = (size_t)nb * Lout * C;
  if (t >= tot) return;
  const int c = (int)(t % C);
  const size_t bp = t / C;
  const int p = (int)(bp % Lout);
  const int b = (int)(bp / Lout);
  const float* s0 = src + ((size_t)b * Lin + 2 * p) * C + c;
  float v = s0[0];
  for (int q = 1; q < win; q++) v = fmaxf(v, s0[(size_t)q * C]);
  dst[t] = v;
}

__global__ void prodmean_kernel(const float* __restrict__ y, const float* __restrict__ z,
                                float* __restrict__ avg, int g0, int nb) {
  const int t = blockIdx.x * 256 + threadIdx.x;
  if (t >= nb * 256) return;
  const int b = t >> 8, j = t & 255;
  const float* yr = y + (size_t)b * 99 * 256 + j;
  const float* zr = z + (size_t)b * 99 * 256 + j;
  float sum = 0.0f;
  for (int p = 0; p < 99; p++) sum += yr[(size_t)p * 256] * zr[(size_t)p * 256];
  avg[(size_t)(g0 + b) * 256 + j] = sum * (1.0f / 99.0f);
}

// ---------------------------------------------------------------------------
extern "C" void kernel_launch(void* const* d_in, const int* in_sizes, int n_in,
                              void* d_out, int out_size, void* d_ws, size_t ws_size,
                              hipStream_t stream) {
  const float* x       = (const float*)d_in[0];
  const int*   ei      = (const int*)d_in[1];
  const int*   et      = (const int*)d_in[2];
  const float* ggnn_W  = (const float*)d_in[3];
  const float* ggnn_b  = (const float*)d_in[4];
  const float* gru_Wih = (const float*)d_in[5];
  const float* gru_Whh = (const float*)d_in[6];
  const float* gru_bih = (const float*)d_in[7];
  const float* gru_bhh = (const float*)d_in[8];
  const float* conv1_w = (const float*)d_in[9];
  const float* conv1_b = (const float*)d_in[10];
  const float* conv2_w = (const float*)d_in[11];
  const float* conv2_b = (const float*)d_in[12];
  const float* cconv1_w = (const float*)d_in[13];
  const float* cconv1_b = (const float*)d_in[14];
  const float* cconv2_w = (const float*)d_in[15];
  const float* cconv2_b = (const float*)d_in[16];
  const float* mlp_y_w = (const float*)d_in[17];
  const float* mlp_y_b = (const float*)d_in[18];
  const float* mlp_z_w = (const float*)d_in[19];
  const float* mlp_z_b = (const float*)d_in[20];
  const float* ml_l1_w = (const float*)d_in[21];
  const float* ml_l1_b = (const float*)d_in[22];
  const float* ml_f1_w = (const float*)d_in[23];
  const float* ml_f1_b = (const float*)d_in[24];
  const float* ml_f2_w = (const float*)d_in[25];
  const float* ml_f2_b = (const float*)d_in[26];
  const float* cls_w   = (const float*)d_in[27];
  const float* cls_b   = (const float*)d_in[28];
  float* out = (float*)d_out;

  // ---------------- workspace layout (bytes) ----------------
  char* base = (char*)d_ws;
  size_t off = 0;
  auto alloc = [&](size_t bytes) { char* p = base + off; off += (bytes + 15) & ~(size_t)15; return p; };
  unsigned short* s   = (unsigned short*)alloc(81920000);  // [NN,400] bf16
  unsigned short* hb1 = (unsigned short*)alloc(40960000);  // mirror buf (odd)
  unsigned short* hb0 = (unsigned short*)alloc(40960000);  // mirror buf (even/final)
  int* eidx    = (int*)alloc(3276800);
  int* rowptr  = (int*)alloc(409604);
  float* cnt2  = (float*)alloc(819200);
  short* WPF   = (short*)alloc(1089536);
  short* WPwc  = (short*)alloc(229376);
  short* WPc1  = (short*)alloc(311296);
  short* WPcc1 = (short*)alloc(737280);
  short* WPc2  = (short*)alloc(114688);
  short* WPcc2 = (short*)alloc(245760);
  short* WPmy  = (short*)alloc(114688);
  short* WPmz  = (short*)alloc(163840);
  short* WPl1  = (short*)alloc(65536);
  short* WPf1  = (short*)alloc(32768);
  short* WPf2  = (short*)alloc(16384);
  short* WPcls = (short*)alloc(32768);
  float* bb  = (float*)alloc(3584);
  float* tt0 = (float*)alloc(3584);
  float* tt1 = (float*)alloc(3584);
  float* avg = (float*)alloc(262144);
  float* h1b = (float*)alloc(131072);
  float* hf1 = (float*)alloc(65536);
  const size_t persist = off;
  float* h = (float*)alloc(81920000);          // optional fp32 GRU carry
  const bool has_h = (ws_size >= off);

  const int fill_blocks = (out_size + 255) / 256;
  if (ws_size < persist) {
    fill_kernel<<<fill_blocks, 256, 0, stream>>>(out, out_size,
                                                 -(float)(ws_size >> 20));
    return;
  }
  float* hptr = has_h ? h : nullptr;

  // setup-only scratch aliased into s (dead before first gather)
  char* ali = (char*)s;
  float* Wcat2 = (float*)(ali);            // 320,000
  float* M1f   = (float*)(ali + 320000);   // 960,000
  float* WFD   = (float*)(ali + 1280000);  // 1,920,000
  float* ta    = (float*)(ali + 3200000);  // 4,800
  int* cnt     = (int*)(ali + 3204800);    // 409,600
  int* ex      = (int*)(ali + 3614400);    // 409,600
  int* bsum    = (int*)(ali + 4024000);    // 1,600
  int* fcur    = (int*)(ali + 4025600);    // 409,600

  fill_kernel<<<fill_blocks, 256, 0, stream>>>(out, out_size, 1.0e4f);

  // ---- setup ----
  pad_h_kernel<<<80000, 256, 0, stream>>>(x, hptr, hb0);
  hipMemsetAsync(cnt, 0, 409600, stream);
  hipMemsetAsync(fcur, 0, 409600, stream);
  hipMemsetAsync(cnt2, 0, 819200, stream);
  hist_kernel<<<3200, 256, 0, stream>>>(ei, cnt);
  scan1_kernel<<<400, 256, 0, stream>>>(cnt, ex, bsum);
  scan2_kernel<<<1, 64, 0, stream>>>(bsum, 400);
  scan3_kernel<<<400, 256, 0, stream>>>(ex, bsum, rowptr);
  fillcsr_kernel<<<3200, 256, 0, stream>>>(ei, et, rowptr, fcur, eidx);
  count_kernel<<<3200, 256, 0, stream>>>(ei, et, cnt2);

  auto packs = [&](const float* W, short* WP, int Nout, int K, int Ntp, int Kp, int CIN) {
    const int total = (Ntp >> 7) * (Kp >> 5) * 512;
    pack_w<<<(total + 255) / 256, 256, 0, stream>>>(W, WP, Nout, K, Ntp, Kp, CIN);
  };
  // M1 = Wih @ Wcat2^T  (600 x 400)
  wcat2_kernel<<<313, 256, 0, stream>>>(ggnn_W, Wcat2);
  packs(Wcat2, WPwc, 400, 200, 512, 224, 0);
  gemm_mfma<0, 0, 0, 0, 0><<<dim3(4, 5), 256, 0, stream>>>(
      gru_Wih, nullptr, WPwc, nullptr, M1f, 600, 400, 200, 7,
      nullptr, nullptr, nullptr, nullptr, nullptr);
  ta_kernel<<<5, 256, 0, stream>>>(gru_Wih, ggnn_b, ta);
  wfd_kernel<<<1875, 256, 0, stream>>>(M1f, gru_Whh, WFD);
  packs(WFD, WPF, 800, 600, 896, 608, 0);
  bbtt_kernel<<<4, 256, 0, stream>>>(gru_bih, gru_bhh, ta, bb, tt0, tt1);
  packs(conv1_w, WPc1,  200, 600, 256, 608, 200);
  packs(cconv1_w,WPcc1, 320, 960, 384, 960, 320);
  packs(conv2_w, WPc2,  200, 200, 256, 224, 0);
  packs(cconv2_w,WPcc2, 320, 320, 384, 320, 0);
  packs(mlp_y_w, WPmy,  256, 200, 256, 224, 0);
  packs(mlp_z_w, WPmz,  256, 320, 256, 320, 0);
  packs(ml_l1_w, WPl1,  128, 256, 128, 256, 0);
  packs(ml_f1_w, WPf1,   64, 128, 128, 128, 0);
  packs(ml_f2_w, WPf2,  128,  64, 128,  64, 0);
  packs(cls_w,   WPcls,   2, 128, 128, 128, 0);

  // ---- GGNN: 8 steps. Fused GEMM launched in 8 row-chunks of 12800 so the
  //      per-chunk A working set (15.4 MB) stays L2-resident across the 7
  //      col-tiles (fix for round-4's 5x A re-fetch from HBM). ----
  unsigned short* hbb[2] = {hb0, hb1};
  for (int step = 0; step < NSTEPS; step++) {
    unsigned short* hcur = hbb[step & 1];
    unsigned short* hnxt = hbb[(step & 1) ^ 1];
    gather_kernel<<<25600, 256, 0, stream>>>(hcur, rowptr, eidx, s);
    for (int c = 0; c < 8; c++) {
      const int n0 = c * 12800;
      gemm_mfma<3, 1, 0, 0, 2><<<dim3(7, 100), 256, 0, stream>>>(
          s + (size_t)n0 * 400, hcur + (size_t)n0 * 200, WPF, bb, nullptr,
          12800, 896, 600, 19,
          tt0, tt1, cnt2 + (size_t)n0 * 2,
          hptr ? hptr + (size_t)n0 * 200 : nullptr,
          hnxt + (size_t)n0 * 200);
    }
  }
  // final mirror is hb0 (after 8 steps)

  // ---- conv/pool/mlp readout, G=64 graphs per chunk (arena = s+hb1) ----
  const int G = 64;
  float* b0  = (float*)s;                          // G*398*320 fp32
  float* b1  = b0 + (size_t)G * 127360;            // G*198*320
  float* b2  = b1 + (size_t)G * 63360;             // G*198*320
  float* y2c = b2 + (size_t)G * 63360;             // G*99*200
  float* z2c = y2c + (size_t)G * 19800;            // G*99*320

  for (int g0 = 0; g0 < BB; g0 += G) {
    const unsigned short* hc = hb0 + (size_t)g0 * LL * HH;
    const float* xc = x + (size_t)g0 * LL * DD;
    const int M1 = G * 398, M2 = G * 198, M3 = G * 99;
    const int gy1 = (M1 + 127) / 128, gy2 = (M2 + 127) / 128, gy3 = (M3 + 127) / 128;
    gemm_mfma<1, 1, 0, 1, 0><<<dim3(2, gy1), 256, 0, stream>>>(
        hc, nullptr, WPc1, conv1_b, b0, M1, 200, 600, 19,
        nullptr, nullptr, nullptr, nullptr, nullptr);
    pool_kernel<<<(int)(((size_t)G * 198 * 200 + 255) / 256), 256, 0, stream>>>(
        b0, b1, G, 398, 198, 200, 3);
    gemm_mfma<0, 0, 0, 1, 0><<<dim3(2, gy2), 256, 0, stream>>>(
        b1, nullptr, WPc2, conv2_b, b2, M2, 200, 200, 7,
        nullptr, nullptr, nullptr, nullptr, nullptr);
    pool_kernel<<<(int)(((size_t)G * 99 * 200 + 255) / 256), 256, 0, stream>>>(
        b2, y2c, G, 198, 99, 200, 2);
    gemm_mfma<2, 1, 0, 1, 0><<<dim3(3, gy1), 256, 0, stream>>>(
        hc, xc, WPcc1, cconv1_b, b0, M1, 320, 960, 30,
        nullptr, nullptr, nullptr, nullptr, nullptr);
    pool_kernel<<<(int)(((size_t)G * 198 * 320 + 255) / 256), 256, 0, stream>>>(
        b0, b1, G, 398, 198, 320, 3);
    gemm_mfma<0, 0, 0, 1, 0><<<dim3(3, gy2), 256, 0, stream>>>(
        b1, nullptr, WPcc2, cconv2_b, b2, M2, 320, 320, 10,
        nullptr, nullptr, nullptr, nullptr, nullptr);
    pool_kernel<<<(int)(((size_t)G * 99 * 320 + 255) / 256), 256, 0, stream>>>(
        b2, z2c, G, 198, 99, 320, 2);
    gemm_mfma<0, 0, 0, 0, 0><<<dim3(2, gy3), 256, 0, stream>>>(
        y2c, nullptr, WPmy, mlp_y_b, b0, M3, 256, 200, 7,
        nullptr, nullptr, nullptr, nullptr, nullptr);
    gemm_mfma<0, 0, 0, 0, 0><<<dim3(2, gy3), 256, 0, stream>>>(
        z2c, nullptr, WPmz, mlp_z_b, b1, M3, 256, 320, 10,
        nullptr, nullptr, nullptr, nullptr, nullptr);
    prodmean_kernel<<<(G * 256 + 255) / 256, 256, 0, stream>>>(b0, b1, avg, g0, G);
  }

  // ---- head ----
  gemm_mfma<0, 0, 0, 1, 0><<<dim3(1, 2), 256, 0, stream>>>(
      avg, nullptr, WPl1, ml_l1_b, h1b, 256, 128, 256, 8,
      nullptr, nullptr, nullptr, nullptr, nullptr);
  gemm_mfma<0, 0, 0, 1, 0><<<dim3(1, 2), 256, 0, stream>>>(
      h1b, nullptr, WPf1, ml_f1_b, hf1, 256, 64, 128, 4,
      nullptr, nullptr, nullptr, nullptr, nullptr);
  gemm_mfma<0, 0, 0, 1, 0><<<dim3(1, 2), 256, 0, stream>>>(
      hf1, nullptr, WPf2, ml_f2_b, out + 512, 256, 128, 64, 2,
      nullptr, nullptr, nullptr, nullptr, nullptr);
  gemm_mfma<0, 0, 0, 0, 0><<<dim3(1, 2), 256, 0, stream>>>(
      out + 512, nullptr, WPcls, cls_b, out, 256, 2, 128, 4,
      nullptr, nullptr, nullptr, nullptr, nullptr);
}

// Round 8
// 6428.716 us; speedup vs baseline: 1.4746x; 1.0141x over previous
//
#include <hip/hip_runtime.h>
#include <hip/hip_bf16.h>
#include <cstdint>
#include <cstddef>

static constexpr int NN = 102400;   // nodes
static constexpr int EE = 819200;   // edges
static constexpr int DD = 120;      // input channels
static constexpr int HH = 200;      // hidden
static constexpr int LL = 400;      // nodes per graph
static constexpr int BB = 256;      // graphs
static constexpr int NSTEPS = 8;

typedef __attribute__((ext_vector_type(8))) short short8;
typedef __attribute__((ext_vector_type(4))) float f32x4;

__device__ __forceinline__ unsigned short f2bf(float f) {
  union { float f; unsigned u; } v; v.f = f;
  return (unsigned short)((v.u + 0x7fffu + ((v.u >> 16) & 1u)) >> 16);
}
__device__ __forceinline__ float bf2f(unsigned short s) {
  union { unsigned u; float f; } v; v.u = ((unsigned)s) << 16; return v.f;
}

__device__ __forceinline__ void gload_lds16(const void* g, void* lds) {
  __builtin_amdgcn_global_load_lds(
      (const __attribute__((address_space(1))) void*)g,
      (__attribute__((address_space(3))) void*)lds, 16, 0, 0);
}

// ---------------------------------------------------------------------------
// Generic MFMA GEMM (setup / conv / head paths) — unchanged, proven.
// ---------------------------------------------------------------------------
template<int AMODE, int ASRC, int OBF, int RELU>
__global__ __launch_bounds__(256) void gemm_mfma(
    const void* __restrict__ Asrc, const void* __restrict__ A2,
    const short* __restrict__ WP, const float* __restrict__ bias,
    void* __restrict__ Cdst, int M, int Nout, int K, int KT)
{
  __shared__ short Asm[4096];
  __shared__ short Bsm[4096];
  const int tid = threadIdx.x;
  const int row0 = blockIdx.y * 128;
  const int col0 = blockIdx.x * 128;

  f32x4 acc[4][4];
#pragma unroll
  for (int mi = 0; mi < 4; mi++)
#pragma unroll
    for (int ni = 0; ni < 4; ni++) acc[mi][ni] = (f32x4){0.f, 0.f, 0.f, 0.f};

  const int r = tid & 15;
  const int kgl = (tid >> 4) & 3;
  const int ghalf = tid >> 6;
  const int w = tid >> 6, l = tid & 63;
  const int wr = w >> 1, wc = w & 1;

  for (int t = 0; t < KT; t++) {
#pragma unroll
    for (int half = 0; half < 2; half++) {
      const int g = ghalf + half * 4;
      int row = row0 + g * 16 + r;
      if (row >= M) row = M - 1;
      const int k0 = t * 32 + kgl * 8;
      short8 sv;
      bool direct = false;
      if (AMODE == 0 && ASRC == 1) {
        if (k0 < K) {
          sv = *reinterpret_cast<const short8*>(
              (const unsigned short*)Asrc + (size_t)row * K + k0);
          direct = true;
        }
      } else if (AMODE == 1) {
        if (k0 < K) {
          const int b = row / 398, tt = row - b * 398;
          const int tap = k0 / 200, i0 = k0 - tap * 200;
          sv = *reinterpret_cast<const short8*>(
              (const unsigned short*)Asrc + ((size_t)(b * 400 + tt + tap)) * 200 + i0);
          direct = true;
        }
      } else if (AMODE == 2) {
        if (k0 < K) {
          const int b = row / 398, tt = row - b * 398;
          const int tap = k0 / 320, c0 = k0 - tap * 320;
          const int node = b * 400 + tt + tap;
          if (c0 < 120) {
            const float* p = (const float*)A2 + (size_t)node * 120 + c0;
            const float4 x0 = *reinterpret_cast<const float4*>(p);
            const float4 x1 = *reinterpret_cast<const float4*>(p + 4);
            sv[0] = (short)f2bf(x0.x); sv[1] = (short)f2bf(x0.y);
            sv[2] = (short)f2bf(x0.z); sv[3] = (short)f2bf(x0.w);
            sv[4] = (short)f2bf(x1.x); sv[5] = (short)f2bf(x1.y);
            sv[6] = (short)f2bf(x1.z); sv[7] = (short)f2bf(x1.w);
            direct = true;
          } else {
            sv = *reinterpret_cast<const short8*>(
                (const unsigned short*)Asrc + (size_t)node * 200 + (c0 - 120));
            direct = true;
          }
        }
      } else {  // AMODE 0, fp32
        if (k0 < K) {
          const float* p = (const float*)Asrc + (size_t)row * K + k0;
          const float4 x0 = *reinterpret_cast<const float4*>(p);
          const float4 x1 = *reinterpret_cast<const float4*>(p + 4);
          sv[0] = (short)f2bf(x0.x); sv[1] = (short)f2bf(x0.y);
          sv[2] = (short)f2bf(x0.z); sv[3] = (short)f2bf(x0.w);
          sv[4] = (short)f2bf(x1.x); sv[5] = (short)f2bf(x1.y);
          sv[6] = (short)f2bf(x1.z); sv[7] = (short)f2bf(x1.w);
          direct = true;
        }
      }
      if (!direct) {
#pragma unroll
        for (int j = 0; j < 8; j++) sv[j] = 0;
      }
      *reinterpret_cast<short8*>(&Asm[(g * 64 + (tid & 63)) * 8]) = sv;
    }
    {
      const size_t wbase = ((size_t)blockIdx.x * KT + t) * 4096;
#pragma unroll
      for (int it = 0; it < 2; it++) {
        const int idx = it * 256 + tid;
        *reinterpret_cast<short8*>(&Bsm[idx * 8]) =
            *reinterpret_cast<const short8*>(WP + wbase + (size_t)idx * 8);
      }
    }
    __syncthreads();
    short8 af[4], bfr[4];
#pragma unroll
    for (int mi = 0; mi < 4; mi++)
      af[mi] = *reinterpret_cast<const short8*>(&Asm[((wr * 4 + mi) * 64 + l) * 8]);
#pragma unroll
    for (int ni = 0; ni < 4; ni++)
      bfr[ni] = *reinterpret_cast<const short8*>(&Bsm[((wc * 4 + ni) * 64 + l) * 8]);
#pragma unroll
    for (int mi = 0; mi < 4; mi++)
#pragma unroll
      for (int ni = 0; ni < 4; ni++)
        acc[mi][ni] = __builtin_amdgcn_mfma_f32_16x16x32_bf16(
            af[mi], bfr[ni], acc[mi][ni], 0, 0, 0);
    __syncthreads();
  }

#pragma unroll
  for (int mi = 0; mi < 4; mi++)
#pragma unroll
    for (int ni = 0; ni < 4; ni++) {
      const int col = col0 + wc * 64 + ni * 16 + (l & 15);
      if (col < Nout) {
        const float bbv = bias ? bias[col] : 0.f;
        const int rbase = row0 + wr * 64 + mi * 16 + ((l >> 4) << 2);
#pragma unroll
        for (int q = 0; q < 4; q++) {
          const int row = rbase + q;
          if (row < M) {
            float val = acc[mi][ni][q] + bbv;
            if (RELU) val = fmaxf(val, 0.f);
            if (OBF)
              ((unsigned short*)Cdst)[(size_t)row * Nout + col] = f2bf(val);
            else
              ((float*)Cdst)[(size_t)row * Nout + col] = val;
          }
        }
      }
    }
}

// ---------------------------------------------------------------------------
// GGNN fused GEMM, m97-style: A [NN,608] bf16 single-source (s2), staged via
// global_load_lds w16 (fragment layout = wave-uniform base + lane*16 by
// construction); B = packed WPF also via global_load_lds. 128x128 tile,
// BK=32, 19 k-tiles, 16 MFMA/wave/tile. XCD-bijective swizzle: 5600 blocks,
// 700/XCD contiguous = 100 row-panels x 7 col-tiles -> A panel L2-resident
// on its XCD (fixes round-4's 5x A re-fetch). Epilogue = fused GRU.
// ---------------------------------------------------------------------------
__global__ __launch_bounds__(256) void ggnn_gemm_kernel(
    const unsigned short* __restrict__ s2,   // [NN,608] bf16
    const short* __restrict__ WPF,           // packed [7][19][8][64][8]
    const float* __restrict__ bbv,
    const float* __restrict__ tt0, const float* __restrict__ tt1,
    const float* __restrict__ cnt2,
    const unsigned short* __restrict__ hbold, // bf16 h (fallback carry)
    float* __restrict__ hout,                 // fp32 carry (may be null)
    unsigned short* __restrict__ hbout)       // bf16 h (next)
{
  __shared__ short Asm[4096];
  __shared__ short Bsm[4096];
  const int tid = threadIdx.x;
  const int w = tid >> 6, l = tid & 63;
  const int wr = w >> 1, wc = w & 1;
  // bijective XCD swizzle (nwg=5600, 8 XCDs, 700 each)
  const int hwid = blockIdx.y * 7 + blockIdx.x;
  const int wgid = (hwid & 7) * 700 + (hwid >> 3);
  const int rowt = wgid / 7;
  const int ct = wgid - rowt * 7;
  const int row0 = rowt * 128;

  f32x4 acc[4][4];
#pragma unroll
  for (int mi = 0; mi < 4; mi++)
#pragma unroll
    for (int ni = 0; ni < 4; ni++) acc[mi][ni] = (f32x4){0.f, 0.f, 0.f, 0.f};

  const int arow = (l & 15);
  const int akol = (l >> 4) * 8;

  for (int t = 0; t < 19; t++) {
#pragma unroll
    for (int gi = 0; gi < 2; gi++) {
      const int g = w + gi * 4;
      const unsigned short* ap =
          s2 + (size_t)(row0 + g * 16 + arow) * 608 + t * 32 + akol;
      gload_lds16(ap, &Asm[g * 512]);
      const short* bp = WPF + ((((size_t)ct * 19 + t) * 8 + g) * 64 + l) * 8;
      gload_lds16(bp, &Bsm[g * 512]);
    }
    __syncthreads();
    short8 af[4], bfr[4];
#pragma unroll
    for (int mi = 0; mi < 4; mi++)
      af[mi] = *reinterpret_cast<const short8*>(&Asm[((wr * 4 + mi) * 64 + l) * 8]);
#pragma unroll
    for (int ni = 0; ni < 4; ni++)
      bfr[ni] = *reinterpret_cast<const short8*>(&Bsm[((wc * 4 + ni) * 64 + l) * 8]);
#pragma unroll
    for (int mi = 0; mi < 4; mi++)
#pragma unroll
      for (int ni = 0; ni < 4; ni++)
        acc[mi][ni] = __builtin_amdgcn_mfma_f32_16x16x32_bf16(
            af[mi], bfr[ni], acc[mi][ni], 0, 0, 0);
    __syncthreads();
  }

  // ---- fused GRU epilogue: cols are 4*ch+gate (r,z,inn,hn) ----
  const int gq = l & 3;
#pragma unroll
  for (int mi = 0; mi < 4; mi++) {
#pragma unroll
    for (int q = 0; q < 4; q++) {
      const int row = row0 + wr * 64 + mi * 16 + ((l >> 4) << 2) + q;
      const float2 cc = *reinterpret_cast<const float2*>(cnt2 + (size_t)row * 2);
#pragma unroll
      for (int ni = 0; ni < 4; ni++) {
        const int col = ct * 128 + wc * 64 + ni * 16 + (l & 15);
        float val = acc[mi][ni][q] + bbv[col] + cc.x * tt0[col] + cc.y * tt1[col];
        float av;
        if (gq == 0 || gq == 1) av = 1.f / (1.f + expf(-val));
        else av = val;
        const float x1 = __shfl_xor(av, 1);   // for gq2: hn (from gq3)
        const float x2 = __shfl_xor(av, 2);   // for gq2: r  (from gq0)
        const float x3 = __shfl_xor(av, 3);   // for gq2: z  (from gq1)
        if (gq == 2 && col < 800) {
          const int ch = col >> 2;
          const float nv = tanhf(av + x2 * x1);
          float hold;
          if (hout) hold = hout[(size_t)row * 200 + ch];
          else hold = bf2f(hbold[(size_t)row * 200 + ch]);
          const float hnew = (1.f - x3) * nv + x3 * hold;
          if (hout) hout[(size_t)row * 200 + ch] = hnew;
          hbout[(size_t)row * 200 + ch] = f2bf(hnew);
        }
      }
    }
  }
}

// ---------------------------------------------------------------------------
__global__ void pack_w(const float* __restrict__ W, short* __restrict__ WP,
                       int Nout, int K, int Ntp, int Kp, int CIN) {
  const int KT = Kp >> 5;
  const int total = (Ntp >> 7) * KT * 512;
  const int u = blockIdx.x * 256 + threadIdx.x;
  if (u >= total) return;
  const int l = u & 63;
  const int g = (u >> 6) & 7;
  const int T = (u >> 9) % KT;
  const int ct = (u >> 9) / KT;
  const int n = ct * 128 + g * 16 + (l & 15);
  const int kb = T * 32 + ((l >> 4) << 3);
  short8 sv;
#pragma unroll
  for (int j = 0; j < 8; j++) {
    const int k = kb + j;
    float v = 0.f;
    if (n < Nout && k < K) {
      if (CIN > 0) {
        const int kw = k / CIN, i = k - kw * CIN;
        v = W[((size_t)n * CIN + i) * 3 + kw];
      } else {
        v = W[(size_t)n * K + k];
      }
    }
    sv[j] = (short)f2bf(v);
  }
  *reinterpret_cast<short8*>(&WP[(size_t)u * 8]) = sv;
}

// ---------------------------------------------------------------------------
__global__ void fill_kernel(float* __restrict__ p, int n, float v) {
  const int t = blockIdx.x * 256 + threadIdx.x;
  if (t < n) p[t] = v;
}

__global__ void pad_h_kernel(const float* __restrict__ x, float* __restrict__ h,
                             unsigned short* __restrict__ hb) {
  const int t = blockIdx.x * 256 + threadIdx.x;
  if (t >= NN * HH) return;
  const int n = t / HH, j = t - n * HH;
  const float v = (j < DD) ? x[(size_t)n * DD + j] : 0.0f;
  if (h) h[t] = v;
  hb[t] = f2bf(v);
}

// ---- CSR build ----
__global__ void hist_kernel(const int* __restrict__ ei, int* __restrict__ cnt) {
  const int e = blockIdx.x * 256 + threadIdx.x;
  if (e < EE) atomicAdd(&cnt[ei[EE + e]], 1);
}
__global__ void scan1_kernel(const int* __restrict__ cnt, int* __restrict__ ex,
                             int* __restrict__ bsum) {
  __shared__ int sm[256];
  const int tid = threadIdx.x;
  const int i = blockIdx.x * 256 + tid;
  const int v = cnt[i];
  sm[tid] = v; __syncthreads();
  for (int off = 1; off < 256; off <<= 1) {
    int t = (tid >= off) ? sm[tid - off] : 0;
    __syncthreads();
    sm[tid] += t;
    __syncthreads();
  }
  ex[i] = sm[tid] - v;
  if (tid == 255) bsum[blockIdx.x] = sm[255];
}
__global__ void scan2_kernel(int* __restrict__ bsum, int nb) {
  if (threadIdx.x == 0 && blockIdx.x == 0) {
    int run = 0;
    for (int b = 0; b < nb; b++) { int t = bsum[b]; bsum[b] = run; run += t; }
  }
}
__global__ void scan3_kernel(const int* __restrict__ ex, const int* __restrict__ bsum,
                             int* __restrict__ rowptr) {
  const int i = blockIdx.x * 256 + threadIdx.x;
  if (i < NN) rowptr[i] = ex[i] + bsum[i >> 8];
  if (i == 0) rowptr[NN] = EE;
}
__global__ void fillcsr_kernel(const int* __restrict__ ei, const int* __restrict__ et,
                               const int* __restrict__ rowptr, int* __restrict__ fcur,
                               int* __restrict__ eidx) {
  const int e = blockIdx.x * 256 + threadIdx.x;
  if (e >= EE) return;
  const int d = ei[EE + e];
  const int pos = atomicAdd(&fcur[d], 1);
  eidx[rowptr[d] + pos] = (ei[e] << 1) | (et[e] & 1);
}
__global__ void count_kernel(const int* __restrict__ ei, const int* __restrict__ et,
                             float* __restrict__ cnt2) {
  const int e = blockIdx.x * 256 + threadIdx.x;
  if (e >= EE) return;
  atomicAdd(&cnt2[(size_t)ei[EE + e] * 2 + (et[e] & 1)], 1.0f);
}

// ---- setup algebra kernels ----
__global__ void wcat2_kernel(const float* __restrict__ gw, float* __restrict__ W2) {
  const int t = blockIdx.x * 256 + threadIdx.x;
  if (t >= 400 * 200) return;
  const int m = t / 200, j = t - m * 200;
  const int ty = (m < 200) ? 0 : 1;
  const int kk = m - ty * 200;
  W2[t] = gw[(size_t)ty * 40000 + j * 200 + kk];
}
__global__ void ta_kernel(const float* __restrict__ wih, const float* __restrict__ gb,
                          float* __restrict__ ta) {
  const int o = blockIdx.x * 256 + threadIdx.x;
  if (o >= 1200) return;
  const int which = o / 600, oo = o - which * 600;
  float s = 0.f;
  for (int j = 0; j < 200; j++) s += wih[(size_t)oo * 200 + j] * gb[which * 200 + j];
  ta[o] = s;
}
__global__ void wfd_kernel(const float* __restrict__ M1, const float* __restrict__ whh,
                           float* __restrict__ WFD) {
  const int t = blockIdx.x * 256 + threadIdx.x;
  if (t >= 800 * 600) return;
  const int c = t / 600, k = t - c * 600;
  const int ch = c >> 2, g = c & 3;
  float v = 0.f;
  if (g == 0) v = (k < 400) ? M1[(size_t)ch * 400 + k] : whh[(size_t)ch * 200 + (k - 400)];
  else if (g == 1) v = (k < 400) ? M1[(size_t)(200 + ch) * 400 + k]
                                 : whh[(size_t)(200 + ch) * 200 + (k - 400)];
  else if (g == 2) v = (k < 400) ? M1[(size_t)(400 + ch) * 400 + k] : 0.f;
  else v = (k < 400) ? 0.f : whh[(size_t)(400 + ch) * 200 + (k - 400)];
  WFD[t] = v;
}
__global__ void bbtt_kernel(const float* __restrict__ bih, const float* __restrict__ bhh,
                            const float* __restrict__ ta, float* __restrict__ bb,
                            float* __restrict__ tt0, float* __restrict__ tt1) {
  const int c = blockIdx.x * 256 + threadIdx.x;
  if (c >= 896) return;
  const int ch = c >> 2, g = c & 3;
  float b = 0.f, t0 = 0.f, t1 = 0.f;
  if (ch < 200) {
    if (g == 0) b = bih[ch] + bhh[ch];
    else if (g == 1) b = bih[200 + ch] + bhh[200 + ch];
    else if (g == 2) b = bih[400 + ch];
    else b = bhh[400 + ch];
    if (g < 3) { t0 = ta[g * 200 + ch]; t1 = ta[600 + g * 200 + ch]; }
  }
  bb[c] = b; tt0[c] = t0; tt1[c] = t1;
}

// ---- CSR gather-sum into s2[N,608]: [sums(400) | hb copy(200) | zeros(8)] ----
__global__ void gather_kernel(const unsigned short* __restrict__ hb,
                              const int* __restrict__ rowptr,
                              const int* __restrict__ eidx,
                              unsigned short* __restrict__ s2) {
  const int nid = blockIdx.x * 4 + (threadIdx.x >> 6);
  const int l = threadIdx.x & 63;
  if (nid >= NN) return;
  const int beg = rowptr[nid], end = rowptr[nid + 1];
  float a00 = 0, a01 = 0, a10 = 0, a11 = 0;
  float b00 = 0, b01 = 0, b10 = 0, b11 = 0;
  const unsigned int* H32 = (const unsigned int*)hb;
  for (int e = beg; e < end; e++) {
    const int pe = eidx[e];
    const int src = pe >> 1, ty = pe & 1;
    const unsigned int* hr = H32 + (size_t)src * 100;
    const unsigned int u0 = hr[l];
    unsigned int u1 = 0;
    if (l < 36) u1 = hr[64 + l];
    const float f0 = bf2f((unsigned short)(u0 & 0xffffu));
    const float f1 = bf2f((unsigned short)(u0 >> 16));
    const float f2 = bf2f((unsigned short)(u1 & 0xffffu));
    const float f3 = bf2f((unsigned short)(u1 >> 16));
    if (ty == 0) { a00 += f0; a01 += f1; a10 += f2; a11 += f3; }
    else         { b00 += f0; b01 += f1; b10 += f2; b11 += f3; }
  }
  unsigned int* S32 = (unsigned int*)s2;
  const size_t rb = (size_t)nid * 304;          // 608 bf16 = 304 u32
  const unsigned int* hn = H32 + (size_t)nid * 100;
  S32[rb + l] = (unsigned int)f2bf(a00) | ((unsigned int)f2bf(a01) << 16);
  S32[rb + 100 + l] = (unsigned int)f2bf(b00) | ((unsigned int)f2bf(b01) << 16);
  S32[rb + 200 + l] = hn[l];
  if (l < 36) {
    S32[rb + 64 + l] = (unsigned int)f2bf(a10) | ((unsigned int)f2bf(a11) << 16);
    S32[rb + 164 + l] = (unsigned int)f2bf(b10) | ((unsigned int)f2bf(b11) << 16);
    S32[rb + 264 + l] = hn[64 + l];
  }
  if (l < 4) S32[rb + 300 + l] = 0;
}

// ---- readout helpers ----
__global__ void pool_kernel(const float* __restrict__ src, float* __restrict__ dst,
                            int nb, int Lin, int Lout, int C, int win) {
  const size_t t = (size_t)blockIdx.x * 256 + threadIdx.x;
  const size_t tot = (size_t)nb * Lout * C;
  if (t >= tot) return;
  const int c = (int)(t % C);
  const size_t bp = t / C;
  const int p = (int)(bp % Lout);
  const int b = (int)(bp / Lout);
  const float* s0 = src + ((size_t)b * Lin + 2 * p) * C + c;
  float v = s0[0];
  for (int q = 1; q < win; q++) v = fmaxf(v, s0[(size_t)q * C]);
  dst[t] = v;
}

__global__ void prodmean_kernel(const float* __restrict__ y, const float* __restrict__ z,
                                float* __restrict__ avg, int g0, int nb) {
  const int t = blockIdx.x * 256 + threadIdx.x;
  if (t >= nb * 256) return;
  const int b = t >> 8, j = t & 255;
  const float* yr = y + (size_t)b * 99 * 256 + j;
  const float* zr = z + (size_t)b * 99 * 256 + j;
  float sum = 0.0f;
  for (int p = 0; p < 99; p++) sum += yr[(size_t)p * 256] * zr[(size_t)p * 256];
  avg[(size_t)(g0 + b) * 256 + j] = sum * (1.0f / 99.0f);
}

// ---------------------------------------------------------------------------
extern "C" void kernel_launch(void* const* d_in, const int* in_sizes, int n_in,
                              void* d_out, int out_size, void* d_ws, size_t ws_size,
                              hipStream_t stream) {
  const float* x       = (const float*)d_in[0];
  const int*   ei      = (const int*)d_in[1];
  const int*   et      = (const int*)d_in[2];
  const float* ggnn_W  = (const float*)d_in[3];
  const float* ggnn_b  = (const float*)d_in[4];
  const float* gru_Wih = (const float*)d_in[5];
  const float* gru_Whh = (const float*)d_in[6];
  const float* gru_bih = (const float*)d_in[7];
  const float* gru_bhh = (const float*)d_in[8];
  const float* conv1_w = (const float*)d_in[9];
  const float* conv1_b = (const float*)d_in[10];
  const float* conv2_w = (const float*)d_in[11];
  const float* conv2_b = (const float*)d_in[12];
  const float* cconv1_w = (const float*)d_in[13];
  const float* cconv1_b = (const float*)d_in[14];
  const float* cconv2_w = (const float*)d_in[15];
  const float* cconv2_b = (const float*)d_in[16];
  const float* mlp_y_w = (const float*)d_in[17];
  const float* mlp_y_b = (const float*)d_in[18];
  const float* mlp_z_w = (const float*)d_in[19];
  const float* mlp_z_b = (const float*)d_in[20];
  const float* ml_l1_w = (const float*)d_in[21];
  const float* ml_l1_b = (const float*)d_in[22];
  const float* ml_f1_w = (const float*)d_in[23];
  const float* ml_f1_b = (const float*)d_in[24];
  const float* ml_f2_w = (const float*)d_in[25];
  const float* ml_f2_b = (const float*)d_in[26];
  const float* cls_w   = (const float*)d_in[27];
  const float* cls_b   = (const float*)d_in[28];
  float* out = (float*)d_out;

  // ---------------- workspace layout (bytes) ----------------
  char* base = (char*)d_ws;
  size_t off = 0;
  auto alloc = [&](size_t bytes) { char* p = base + off; off += (bytes + 15) & ~(size_t)15; return p; };
  unsigned short* s2  = (unsigned short*)alloc(124518400); // [NN,608] bf16
  unsigned short* hb1 = (unsigned short*)alloc(40960000);  // mirror buf (odd)
  unsigned short* hb0 = (unsigned short*)alloc(40960000);  // mirror buf (even/final)
  int* eidx    = (int*)alloc(3276800);
  int* rowptr  = (int*)alloc(409604);
  float* cnt2  = (float*)alloc(819200);
  short* WPF   = (short*)alloc(1089536);
  short* WPwc  = (short*)alloc(229376);
  short* WPc1  = (short*)alloc(311296);
  short* WPcc1 = (short*)alloc(737280);
  short* WPc2  = (short*)alloc(114688);
  short* WPcc2 = (short*)alloc(245760);
  short* WPmy  = (short*)alloc(114688);
  short* WPmz  = (short*)alloc(163840);
  short* WPl1  = (short*)alloc(65536);
  short* WPf1  = (short*)alloc(32768);
  short* WPf2  = (short*)alloc(16384);
  short* WPcls = (short*)alloc(32768);
  float* bb  = (float*)alloc(3584);
  float* tt0 = (float*)alloc(3584);
  float* tt1 = (float*)alloc(3584);
  float* avg = (float*)alloc(262144);
  float* h1b = (float*)alloc(131072);
  float* hf1 = (float*)alloc(65536);
  const size_t persist = off;
  float* h = (float*)alloc(81920000);          // optional fp32 GRU carry
  const bool has_h = (ws_size >= off);

  const int fill_blocks = (out_size + 255) / 256;
  if (ws_size < persist) {
    fill_kernel<<<fill_blocks, 256, 0, stream>>>(out, out_size,
                                                 -(float)(ws_size >> 20));
    return;
  }
  float* hptr = has_h ? h : nullptr;

  // setup-only scratch aliased into s2 (dead before first gather)
  char* ali = (char*)s2;
  float* Wcat2 = (float*)(ali);            // 320,000
  float* M1f   = (float*)(ali + 320000);   // 960,000
  float* WFD   = (float*)(ali + 1280000);  // 1,920,000
  float* ta    = (float*)(ali + 3200000);  // 4,800
  int* cnt     = (int*)(ali + 3204800);    // 409,600
  int* ex      = (int*)(ali + 3614400);    // 409,600
  int* bsum    = (int*)(ali + 4024000);    // 1,600
  int* fcur    = (int*)(ali + 4025600);    // 409,600

  fill_kernel<<<fill_blocks, 256, 0, stream>>>(out, out_size, 1.0e4f);

  // ---- setup ----
  pad_h_kernel<<<80000, 256, 0, stream>>>(x, hptr, hb0);
  hipMemsetAsync(cnt, 0, 409600, stream);
  hipMemsetAsync(fcur, 0, 409600, stream);
  hipMemsetAsync(cnt2, 0, 819200, stream);
  hist_kernel<<<3200, 256, 0, stream>>>(ei, cnt);
  scan1_kernel<<<400, 256, 0, stream>>>(cnt, ex, bsum);
  scan2_kernel<<<1, 64, 0, stream>>>(bsum, 400);
  scan3_kernel<<<400, 256, 0, stream>>>(ex, bsum, rowptr);
  fillcsr_kernel<<<3200, 256, 0, stream>>>(ei, et, rowptr, fcur, eidx);
  count_kernel<<<3200, 256, 0, stream>>>(ei, et, cnt2);

  auto packs = [&](const float* W, short* WP, int Nout, int K, int Ntp, int Kp, int CIN) {
    const int total = (Ntp >> 7) * (Kp >> 5) * 512;
    pack_w<<<(total + 255) / 256, 256, 0, stream>>>(W, WP, Nout, K, Ntp, Kp, CIN);
  };
  // M1 = Wih @ Wcat2^T  (600 x 400)
  wcat2_kernel<<<313, 256, 0, stream>>>(ggnn_W, Wcat2);
  packs(Wcat2, WPwc, 400, 200, 512, 224, 0);
  gemm_mfma<0, 0, 0, 0><<<dim3(4, 5), 256, 0, stream>>>(
      gru_Wih, nullptr, WPwc, nullptr, M1f, 600, 400, 200, 7);
  ta_kernel<<<5, 256, 0, stream>>>(gru_Wih, ggnn_b, ta);
  wfd_kernel<<<1875, 256, 0, stream>>>(M1f, gru_Whh, WFD);
  packs(WFD, WPF, 800, 600, 896, 608, 0);
  bbtt_kernel<<<4, 256, 0, stream>>>(gru_bih, gru_bhh, ta, bb, tt0, tt1);
  packs(conv1_w, WPc1,  200, 600, 256, 608, 200);
  packs(cconv1_w,WPcc1, 320, 960, 384, 960, 320);
  packs(conv2_w, WPc2,  200, 200, 256, 224, 0);
  packs(cconv2_w,WPcc2, 320, 320, 384, 320, 0);
  packs(mlp_y_w, WPmy,  256, 200, 256, 224, 0);
  packs(mlp_z_w, WPmz,  256, 320, 256, 320, 0);
  packs(ml_l1_w, WPl1,  128, 256, 128, 256, 0);
  packs(ml_f1_w, WPf1,   64, 128, 128, 128, 0);
  packs(ml_f2_w, WPf2,  128,  64, 128,  64, 0);
  packs(cls_w,   WPcls,   2, 128, 128, 128, 0);

  // ---- GGNN: 8 steps, 2 kernels each ----
  unsigned short* hbb[2] = {hb0, hb1};
  for (int step = 0; step < NSTEPS; step++) {
    unsigned short* hcur = hbb[step & 1];
    unsigned short* hnxt = hbb[(step & 1) ^ 1];
    gather_kernel<<<25600, 256, 0, stream>>>(hcur, rowptr, eidx, s2);
    ggnn_gemm_kernel<<<dim3(7, 800), 256, 0, stream>>>(
        s2, WPF, bb, tt0, tt1, cnt2, hcur, hptr, hnxt);
  }
  // final mirror is hb0 (after 8 steps)

  // ---- conv/pool/mlp readout, G=64 graphs per chunk (arena = s2) ----
  const int G = 64;
  float* b0  = (float*)s2;                         // G*398*320 fp32
  float* b1  = b0 + (size_t)G * 127360;            // G*198*320
  float* b2  = b1 + (size_t)G * 63360;             // G*198*320
  float* y2c = b2 + (size_t)G * 63360;             // G*99*200
  float* z2c = y2c + (size_t)G * 19800;            // G*99*320

  for (int g0 = 0; g0 < BB; g0 += G) {
    const unsigned short* hc = hb0 + (size_t)g0 * LL * HH;
    const float* xc = x + (size_t)g0 * LL * DD;
    const int M1 = G * 398, M2 = G * 198, M3 = G * 99;
    const int gy1 = (M1 + 127) / 128, gy2 = (M2 + 127) / 128, gy3 = (M3 + 127) / 128;
    gemm_mfma<1, 1, 0, 1><<<dim3(2, gy1), 256, 0, stream>>>(
        hc, nullptr, WPc1, conv1_b, b0, M1, 200, 600, 19);
    pool_kernel<<<(int)(((size_t)G * 198 * 200 + 255) / 256), 256, 0, stream>>>(
        b0, b1, G, 398, 198, 200, 3);
    gemm_mfma<0, 0, 0, 1><<<dim3(2, gy2), 256, 0, stream>>>(
        b1, nullptr, WPc2, conv2_b, b2, M2, 200, 200, 7);
    pool_kernel<<<(int)(((size_t)G * 99 * 200 + 255) / 256), 256, 0, stream>>>(
        b2, y2c, G, 198, 99, 200, 2);
    gemm_mfma<2, 1, 0, 1><<<dim3(3, gy1), 256, 0, stream>>>(
        hc, xc, WPcc1, cconv1_b, b0, M1, 320, 960, 30);
    pool_kernel<<<(int)(((size_t)G * 198 * 320 + 255) / 256), 256, 0, stream>>>(
        b0, b1, G, 398, 198, 320, 3);
    gemm_mfma<0, 0, 0, 1><<<dim3(3, gy2), 256, 0, stream>>>(
        b1, nullptr, WPcc2, cconv2_b, b2, M2, 320, 320, 10);
    pool_kernel<<<(int)(((size_t)G * 99 * 320 + 255) / 256), 256, 0, stream>>>(
        b2, z2c, G, 198, 99, 320, 2);
    gemm_mfma<0, 0, 0, 0><<<dim3(2, gy3), 256, 0, stream>>>(
        y2c, nullptr, WPmy, mlp_y_b, b0, M3, 256, 200, 7);
    gemm_mfma<0, 0, 0, 0><<<dim3(2, gy3), 256, 0, stream>>>(
        z2c, nullptr, WPmz, mlp_z_b, b1, M3, 256, 320, 10);
    prodmean_kernel<<<(G * 256 + 255) / 256, 256, 0, stream>>>(b0, b1, avg, g0, G);
  }

  // ---- head ----
  gemm_mfma<0, 0, 0, 1><<<dim3(1, 2), 256, 0, stream>>>(
      avg, nullptr, WPl1, ml_l1_b, h1b, 256, 128, 256, 8);
  gemm_mfma<0, 0, 0, 1><<<dim3(1, 2), 256, 0, stream>>>(
      h1b, nullptr, WPf1, ml_f1_b, hf1, 256, 64, 128, 4);
  gemm_mfma<0, 0, 0, 1><<<dim3(1, 2), 256, 0, stream>>>(
      hf1, nullptr, WPf2, ml_f2_b, out + 512, 256, 128, 64, 2);
  gemm_mfma<0, 0, 0, 0><<<dim3(1, 2), 256, 0, stream>>>(
      out + 512, nullptr, WPcls, cls_b, out, 256, 2, 128, 4);
}

// Round 9
// 4922.026 us; speedup vs baseline: 1.9261x; 1.3061x over previous
//
#include <hip/hip_runtime.h>
#include <hip/hip_bf16.h>
#include <cstdint>
#include <cstddef>

static constexpr int NN = 102400;   // nodes
static constexpr int EE = 819200;   // edges
static constexpr int DD = 120;      // input channels
static constexpr int HH = 200;      // hidden
static constexpr int LL = 400;      // nodes per graph
static constexpr int BB = 256;      // graphs
static constexpr int NSTEPS = 8;

typedef __attribute__((ext_vector_type(8))) short short8;
typedef __attribute__((ext_vector_type(4))) float f32x4;

__device__ __forceinline__ unsigned short f2bf(float f) {
  union { float f; unsigned u; } v; v.f = f;
  return (unsigned short)((v.u + 0x7fffu + ((v.u >> 16) & 1u)) >> 16);
}
__device__ __forceinline__ float bf2f(unsigned short s) {
  union { unsigned u; float f; } v; v.u = ((unsigned)s) << 16; return v.f;
}
// fast sigmoid / tanh via native v_exp_f32 (2^x) + v_rcp_f32
__device__ __forceinline__ float fast_sigmoid(float x) {
  return __builtin_amdgcn_rcpf(1.f + __builtin_exp2f(-1.44269504f * x));
}
__device__ __forceinline__ float fast_tanh(float x) {
  return 1.f - 2.f * __builtin_amdgcn_rcpf(1.f + __builtin_exp2f(2.88539008f * x));
}

// ---------------------------------------------------------------------------
// Generic MFMA GEMM (setup / conv / head paths) — unchanged, proven.
// ---------------------------------------------------------------------------
template<int AMODE, int ASRC, int OBF, int RELU>
__global__ __launch_bounds__(256) void gemm_mfma(
    const void* __restrict__ Asrc, const void* __restrict__ A2,
    const short* __restrict__ WP, const float* __restrict__ bias,
    void* __restrict__ Cdst, int M, int Nout, int K, int KT)
{
  __shared__ short Asm[4096];
  __shared__ short Bsm[4096];
  const int tid = threadIdx.x;
  const int row0 = blockIdx.y * 128;
  const int col0 = blockIdx.x * 128;

  f32x4 acc[4][4];
#pragma unroll
  for (int mi = 0; mi < 4; mi++)
#pragma unroll
    for (int ni = 0; ni < 4; ni++) acc[mi][ni] = (f32x4){0.f, 0.f, 0.f, 0.f};

  const int r = tid & 15;
  const int kgl = (tid >> 4) & 3;
  const int ghalf = tid >> 6;
  const int w = tid >> 6, l = tid & 63;
  const int wr = w >> 1, wc = w & 1;

  for (int t = 0; t < KT; t++) {
#pragma unroll
    for (int half = 0; half < 2; half++) {
      const int g = ghalf + half * 4;
      int row = row0 + g * 16 + r;
      if (row >= M) row = M - 1;
      const int k0 = t * 32 + kgl * 8;
      short8 sv;
      bool direct = false;
      if (AMODE == 0 && ASRC == 1) {
        if (k0 < K) {
          sv = *reinterpret_cast<const short8*>(
              (const unsigned short*)Asrc + (size_t)row * K + k0);
          direct = true;
        }
      } else if (AMODE == 1) {
        if (k0 < K) {
          const int b = row / 398, tt = row - b * 398;
          const int tap = k0 / 200, i0 = k0 - tap * 200;
          sv = *reinterpret_cast<const short8*>(
              (const unsigned short*)Asrc + ((size_t)(b * 400 + tt + tap)) * 200 + i0);
          direct = true;
        }
      } else if (AMODE == 2) {
        if (k0 < K) {
          const int b = row / 398, tt = row - b * 398;
          const int tap = k0 / 320, c0 = k0 - tap * 320;
          const int node = b * 400 + tt + tap;
          if (c0 < 120) {
            const float* p = (const float*)A2 + (size_t)node * 120 + c0;
            const float4 x0 = *reinterpret_cast<const float4*>(p);
            const float4 x1 = *reinterpret_cast<const float4*>(p + 4);
            sv[0] = (short)f2bf(x0.x); sv[1] = (short)f2bf(x0.y);
            sv[2] = (short)f2bf(x0.z); sv[3] = (short)f2bf(x0.w);
            sv[4] = (short)f2bf(x1.x); sv[5] = (short)f2bf(x1.y);
            sv[6] = (short)f2bf(x1.z); sv[7] = (short)f2bf(x1.w);
            direct = true;
          } else {
            sv = *reinterpret_cast<const short8*>(
                (const unsigned short*)Asrc + (size_t)node * 200 + (c0 - 120));
            direct = true;
          }
        }
      } else {  // AMODE 0, fp32
        if (k0 < K) {
          const float* p = (const float*)Asrc + (size_t)row * K + k0;
          const float4 x0 = *reinterpret_cast<const float4*>(p);
          const float4 x1 = *reinterpret_cast<const float4*>(p + 4);
          sv[0] = (short)f2bf(x0.x); sv[1] = (short)f2bf(x0.y);
          sv[2] = (short)f2bf(x0.z); sv[3] = (short)f2bf(x0.w);
          sv[4] = (short)f2bf(x1.x); sv[5] = (short)f2bf(x1.y);
          sv[6] = (short)f2bf(x1.z); sv[7] = (short)f2bf(x1.w);
          direct = true;
        }
      }
      if (!direct) {
#pragma unroll
        for (int j = 0; j < 8; j++) sv[j] = 0;
      }
      *reinterpret_cast<short8*>(&Asm[(g * 64 + (tid & 63)) * 8]) = sv;
    }
    {
      const size_t wbase = ((size_t)blockIdx.x * KT + t) * 4096;
#pragma unroll
      for (int it = 0; it < 2; it++) {
        const int idx = it * 256 + tid;
        *reinterpret_cast<short8*>(&Bsm[idx * 8]) =
            *reinterpret_cast<const short8*>(WP + wbase + (size_t)idx * 8);
      }
    }
    __syncthreads();
    short8 af[4], bfr[4];
#pragma unroll
    for (int mi = 0; mi < 4; mi++)
      af[mi] = *reinterpret_cast<const short8*>(&Asm[((wr * 4 + mi) * 64 + l) * 8]);
#pragma unroll
    for (int ni = 0; ni < 4; ni++)
      bfr[ni] = *reinterpret_cast<const short8*>(&Bsm[((wc * 4 + ni) * 64 + l) * 8]);
#pragma unroll
    for (int mi = 0; mi < 4; mi++)
#pragma unroll
      for (int ni = 0; ni < 4; ni++)
        acc[mi][ni] = __builtin_amdgcn_mfma_f32_16x16x32_bf16(
            af[mi], bfr[ni], acc[mi][ni], 0, 0, 0);
    __syncthreads();
  }

#pragma unroll
  for (int mi = 0; mi < 4; mi++)
#pragma unroll
    for (int ni = 0; ni < 4; ni++) {
      const int col = col0 + wc * 64 + ni * 16 + (l & 15);
      if (col < Nout) {
        const float bbv = bias ? bias[col] : 0.f;
        const int rbase = row0 + wr * 64 + mi * 16 + ((l >> 4) << 2);
#pragma unroll
        for (int q = 0; q < 4; q++) {
          const int row = rbase + q;
          if (row < M) {
            float val = acc[mi][ni][q] + bbv;
            if (RELU) val = fmaxf(val, 0.f);
            if (OBF)
              ((unsigned short*)Cdst)[(size_t)row * Nout + col] = f2bf(val);
            else
              ((float*)Cdst)[(size_t)row * Nout + col] = val;
          }
        }
      }
    }
}

// ---------------------------------------------------------------------------
// GGNN fused GEMM, round 9: BARRIER-FREE register streaming. Per-XCD A panels
// are L2-resident (round-8 swizzle, FETCH=86MB proven), so each wave loads its
// MFMA fragments directly global->VGPR: A = per-lane 16B gathers, B = packed
// fragment-major fully-coalesced 16B loads. No LDS, no __syncthreads in the
// main loop; explicit 1-deep register double-buffer. Epilogue = fused GRU
// with native exp2/rcp sigmoid+tanh.
// ---------------------------------------------------------------------------
__global__ __launch_bounds__(256) void ggnn_gemm_kernel(
    const unsigned short* __restrict__ s2,   // [NN,608] bf16
    const short* __restrict__ WPF,           // packed [7][19][8][64][8]
    const float* __restrict__ bbv,
    const float* __restrict__ tt0, const float* __restrict__ tt1,
    const float* __restrict__ cnt2,
    const unsigned short* __restrict__ hbold, // bf16 h (fallback carry)
    float* __restrict__ hout,                 // fp32 carry (may be null)
    unsigned short* __restrict__ hbout)       // bf16 h (next)
{
  const int tid = threadIdx.x;
  const int w = tid >> 6, l = tid & 63;
  const int wr = w >> 1, wc = w & 1;
  // bijective XCD swizzle (nwg=5600, 8 XCDs, 700 each)
  const int hwid = blockIdx.y * 7 + blockIdx.x;
  const int wgid = (hwid & 7) * 700 + (hwid >> 3);
  const int rowt = wgid / 7;
  const int ct = wgid - rowt * 7;
  const int row0 = rowt * 128;

  f32x4 acc[4][4];
#pragma unroll
  for (int mi = 0; mi < 4; mi++)
#pragma unroll
    for (int ni = 0; ni < 4; ni++) acc[mi][ni] = (f32x4){0.f, 0.f, 0.f, 0.f};

  // per-lane fragment base pointers
  const unsigned short* abase =
      s2 + (size_t)(row0 + wr * 64 + (l & 15)) * 608 + (l >> 4) * 8;
  const short* bbase =
      WPF + ((((size_t)ct * 19) * 8 + (size_t)wc * 4) * 64 + (size_t)l) * 8;

  short8 afc[4], bfc[4], afn[4], bfn[4];
#pragma unroll
  for (int mi = 0; mi < 4; mi++)
    afc[mi] = *reinterpret_cast<const short8*>(abase + (size_t)mi * 16 * 608);
#pragma unroll
  for (int ni = 0; ni < 4; ni++)
    bfc[ni] = *reinterpret_cast<const short8*>(bbase + (size_t)ni * 512);

#pragma unroll
  for (int t = 0; t < 19; t++) {
    if (t < 18) {
#pragma unroll
      for (int mi = 0; mi < 4; mi++)
        afn[mi] = *reinterpret_cast<const short8*>(
            abase + (size_t)mi * 16 * 608 + (t + 1) * 32);
#pragma unroll
      for (int ni = 0; ni < 4; ni++)
        bfn[ni] = *reinterpret_cast<const short8*>(
            bbase + (size_t)(t + 1) * 4096 + (size_t)ni * 512);
    }
#pragma unroll
    for (int mi = 0; mi < 4; mi++)
#pragma unroll
      for (int ni = 0; ni < 4; ni++)
        acc[mi][ni] = __builtin_amdgcn_mfma_f32_16x16x32_bf16(
            afc[mi], bfc[ni], acc[mi][ni], 0, 0, 0);
#pragma unroll
    for (int mi = 0; mi < 4; mi++) afc[mi] = afn[mi];
#pragma unroll
    for (int ni = 0; ni < 4; ni++) bfc[ni] = bfn[ni];
  }

  // ---- fused GRU epilogue: cols are 4*ch+gate (r,z,inn,hn) ----
  const int gq = l & 3;
#pragma unroll
  for (int mi = 0; mi < 4; mi++) {
#pragma unroll
    for (int q = 0; q < 4; q++) {
      const int row = row0 + wr * 64 + mi * 16 + ((l >> 4) << 2) + q;
      const float2 cc = *reinterpret_cast<const float2*>(cnt2 + (size_t)row * 2);
#pragma unroll
      for (int ni = 0; ni < 4; ni++) {
        const int col = ct * 128 + wc * 64 + ni * 16 + (l & 15);
        float val = acc[mi][ni][q] + bbv[col] + cc.x * tt0[col] + cc.y * tt1[col];
        float av;
        if (gq == 0 || gq == 1) av = fast_sigmoid(val);
        else av = val;
        const float x1 = __shfl_xor(av, 1);   // for gq2: hn (from gq3)
        const float x2 = __shfl_xor(av, 2);   // for gq2: r  (from gq0)
        const float x3 = __shfl_xor(av, 3);   // for gq2: z  (from gq1)
        if (gq == 2 && col < 800) {
          const int ch = col >> 2;
          const float nv = fast_tanh(av + x2 * x1);
          float hold;
          if (hout) hold = hout[(size_t)row * 200 + ch];
          else hold = bf2f(hbold[(size_t)row * 200 + ch]);
          const float hnew = (1.f - x3) * nv + x3 * hold;
          if (hout) hout[(size_t)row * 200 + ch] = hnew;
          hbout[(size_t)row * 200 + ch] = f2bf(hnew);
        }
      }
    }
  }
}

// ---------------------------------------------------------------------------
__global__ void pack_w(const float* __restrict__ W, short* __restrict__ WP,
                       int Nout, int K, int Ntp, int Kp, int CIN) {
  const int KT = Kp >> 5;
  const int total = (Ntp >> 7) * KT * 512;
  const int u = blockIdx.x * 256 + threadIdx.x;
  if (u >= total) return;
  const int l = u & 63;
  const int g = (u >> 6) & 7;
  const int T = (u >> 9) % KT;
  const int ct = (u >> 9) / KT;
  const int n = ct * 128 + g * 16 + (l & 15);
  const int kb = T * 32 + ((l >> 4) << 3);
  short8 sv;
#pragma unroll
  for (int j = 0; j < 8; j++) {
    const int k = kb + j;
    float v = 0.f;
    if (n < Nout && k < K) {
      if (CIN > 0) {
        const int kw = k / CIN, i = k - kw * CIN;
        v = W[((size_t)n * CIN + i) * 3 + kw];
      } else {
        v = W[(size_t)n * K + k];
      }
    }
    sv[j] = (short)f2bf(v);
  }
  *reinterpret_cast<short8*>(&WP[(size_t)u * 8]) = sv;
}

// ---------------------------------------------------------------------------
__global__ void fill_kernel(float* __restrict__ p, int n, float v) {
  const int t = blockIdx.x * 256 + threadIdx.x;
  if (t < n) p[t] = v;
}

__global__ void pad_h_kernel(const float* __restrict__ x, float* __restrict__ h,
                             unsigned short* __restrict__ hb) {
  const int t = blockIdx.x * 256 + threadIdx.x;
  if (t >= NN * HH) return;
  const int n = t / HH, j = t - n * HH;
  const float v = (j < DD) ? x[(size_t)n * DD + j] : 0.0f;
  if (h) h[t] = v;
  hb[t] = f2bf(v);
}

// ---- CSR build ----
__global__ void hist_kernel(const int* __restrict__ ei, int* __restrict__ cnt) {
  const int e = blockIdx.x * 256 + threadIdx.x;
  if (e < EE) atomicAdd(&cnt[ei[EE + e]], 1);
}
__global__ void scan1_kernel(const int* __restrict__ cnt, int* __restrict__ ex,
                             int* __restrict__ bsum) {
  __shared__ int sm[256];
  const int tid = threadIdx.x;
  const int i = blockIdx.x * 256 + tid;
  const int v = cnt[i];
  sm[tid] = v; __syncthreads();
  for (int off = 1; off < 256; off <<= 1) {
    int t = (tid >= off) ? sm[tid - off] : 0;
    __syncthreads();
    sm[tid] += t;
    __syncthreads();
  }
  ex[i] = sm[tid] - v;
  if (tid == 255) bsum[blockIdx.x] = sm[255];
}
__global__ void scan2_kernel(int* __restrict__ bsum, int nb) {
  if (threadIdx.x == 0 && blockIdx.x == 0) {
    int run = 0;
    for (int b = 0; b < nb; b++) { int t = bsum[b]; bsum[b] = run; run += t; }
  }
}
__global__ void scan3_kernel(const int* __restrict__ ex, const int* __restrict__ bsum,
                             int* __restrict__ rowptr) {
  const int i = blockIdx.x * 256 + threadIdx.x;
  if (i < NN) rowptr[i] = ex[i] + bsum[i >> 8];
  if (i == 0) rowptr[NN] = EE;
}
__global__ void fillcsr_kernel(const int* __restrict__ ei, const int* __restrict__ et,
                               const int* __restrict__ rowptr, int* __restrict__ fcur,
                               int* __restrict__ eidx) {
  const int e = blockIdx.x * 256 + threadIdx.x;
  if (e >= EE) return;
  const int d = ei[EE + e];
  const int pos = atomicAdd(&fcur[d], 1);
  eidx[rowptr[d] + pos] = (ei[e] << 1) | (et[e] & 1);
}
__global__ void count_kernel(const int* __restrict__ ei, const int* __restrict__ et,
                             float* __restrict__ cnt2) {
  const int e = blockIdx.x * 256 + threadIdx.x;
  if (e >= EE) return;
  atomicAdd(&cnt2[(size_t)ei[EE + e] * 2 + (et[e] & 1)], 1.0f);
}

// ---- setup algebra kernels ----
__global__ void wcat2_kernel(const float* __restrict__ gw, float* __restrict__ W2) {
  const int t = blockIdx.x * 256 + threadIdx.x;
  if (t >= 400 * 200) return;
  const int m = t / 200, j = t - m * 200;
  const int ty = (m < 200) ? 0 : 1;
  const int kk = m - ty * 200;
  W2[t] = gw[(size_t)ty * 40000 + j * 200 + kk];
}
__global__ void ta_kernel(const float* __restrict__ wih, const float* __restrict__ gb,
                          float* __restrict__ ta) {
  const int o = blockIdx.x * 256 + threadIdx.x;
  if (o >= 1200) return;
  const int which = o / 600, oo = o - which * 600;
  float s = 0.f;
  for (int j = 0; j < 200; j++) s += wih[(size_t)oo * 200 + j] * gb[which * 200 + j];
  ta[o] = s;
}
__global__ void wfd_kernel(const float* __restrict__ M1, const float* __restrict__ whh,
                           float* __restrict__ WFD) {
  const int t = blockIdx.x * 256 + threadIdx.x;
  if (t >= 800 * 600) return;
  const int c = t / 600, k = t - c * 600;
  const int ch = c >> 2, g = c & 3;
  float v = 0.f;
  if (g == 0) v = (k < 400) ? M1[(size_t)ch * 400 + k] : whh[(size_t)ch * 200 + (k - 400)];
  else if (g == 1) v = (k < 400) ? M1[(size_t)(200 + ch) * 400 + k]
                                 : whh[(size_t)(200 + ch) * 200 + (k - 400)];
  else if (g == 2) v = (k < 400) ? M1[(size_t)(400 + ch) * 400 + k] : 0.f;
  else v = (k < 400) ? 0.f : whh[(size_t)(400 + ch) * 200 + (k - 400)];
  WFD[t] = v;
}
__global__ void bbtt_kernel(const float* __restrict__ bih, const float* __restrict__ bhh,
                            const float* __restrict__ ta, float* __restrict__ bb,
                            float* __restrict__ tt0, float* __restrict__ tt1) {
  const int c = blockIdx.x * 256 + threadIdx.x;
  if (c >= 896) return;
  const int ch = c >> 2, g = c & 3;
  float b = 0.f, t0 = 0.f, t1 = 0.f;
  if (ch < 200) {
    if (g == 0) b = bih[ch] + bhh[ch];
    else if (g == 1) b = bih[200 + ch] + bhh[200 + ch];
    else if (g == 2) b = bih[400 + ch];
    else b = bhh[400 + ch];
    if (g < 3) { t0 = ta[g * 200 + ch]; t1 = ta[600 + g * 200 + ch]; }
  }
  bb[c] = b; tt0[c] = t0; tt1[c] = t1;
}

// ---- CSR gather-sum into s2[N,608]: [sums(400) | hb copy(200) | zeros(8)] ----
__global__ void gather_kernel(const unsigned short* __restrict__ hb,
                              const int* __restrict__ rowptr,
                              const int* __restrict__ eidx,
                              unsigned short* __restrict__ s2) {
  const int nid = blockIdx.x * 4 + (threadIdx.x >> 6);
  const int l = threadIdx.x & 63;
  if (nid >= NN) return;
  const int beg = rowptr[nid], end = rowptr[nid + 1];
  float a00 = 0, a01 = 0, a10 = 0, a11 = 0;
  float b00 = 0, b01 = 0, b10 = 0, b11 = 0;
  const unsigned int* H32 = (const unsigned int*)hb;
  for (int e = beg; e < end; e++) {
    const int pe = eidx[e];
    const int src = pe >> 1, ty = pe & 1;
    const unsigned int* hr = H32 + (size_t)src * 100;
    const unsigned int u0 = hr[l];
    unsigned int u1 = 0;
    if (l < 36) u1 = hr[64 + l];
    const float f0 = bf2f((unsigned short)(u0 & 0xffffu));
    const float f1 = bf2f((unsigned short)(u0 >> 16));
    const float f2 = bf2f((unsigned short)(u1 & 0xffffu));
    const float f3 = bf2f((unsigned short)(u1 >> 16));
    if (ty == 0) { a00 += f0; a01 += f1; a10 += f2; a11 += f3; }
    else         { b00 += f0; b01 += f1; b10 += f2; b11 += f3; }
  }
  unsigned int* S32 = (unsigned int*)s2;
  const size_t rb = (size_t)nid * 304;          // 608 bf16 = 304 u32
  const unsigned int* hn = H32 + (size_t)nid * 100;
  S32[rb + l] = (unsigned int)f2bf(a00) | ((unsigned int)f2bf(a01) << 16);
  S32[rb + 100 + l] = (unsigned int)f2bf(b00) | ((unsigned int)f2bf(b01) << 16);
  S32[rb + 200 + l] = hn[l];
  if (l < 36) {
    S32[rb + 64 + l] = (unsigned int)f2bf(a10) | ((unsigned int)f2bf(a11) << 16);
    S32[rb + 164 + l] = (unsigned int)f2bf(b10) | ((unsigned int)f2bf(b11) << 16);
    S32[rb + 264 + l] = hn[64 + l];
  }
  if (l < 4) S32[rb + 300 + l] = 0;
}

// ---- readout helpers ----
__global__ void pool_kernel(const float* __restrict__ src, float* __restrict__ dst,
                            int nb, int Lin, int Lout, int C, int win) {
  const size_t t = (size_t)blockIdx.x * 256 + threadIdx.x;
  const size_t tot = (size_t)nb * Lout * C;
  if (t >= tot) return;
  const int c = (int)(t % C);
  const size_t bp = t / C;
  const int p = (int)(bp % Lout);
  const int b = (int)(bp / Lout);
  const float* s0 = src + ((size_t)b * Lin + 2 * p) * C + c;
  float v = s0[0];
  for (int q = 1; q < win; q++) v = fmaxf(v, s0[(size_t)q * C]);
  dst[t] = v;
}

__global__ void prodmean_kernel(const float* __restrict__ y, const float* __restrict__ z,
                                float* __restrict__ avg, int g0, int nb) {
  const int t = blockIdx.x * 256 + threadIdx.x;
  if (t >= nb * 256) return;
  const int b = t >> 8, j = t & 255;
  const float* yr = y + (size_t)b * 99 * 256 + j;
  const float* zr = z + (size_t)b * 99 * 256 + j;
  float sum = 0.0f;
  for (int p = 0; p < 99; p++) sum += yr[(size_t)p * 256] * zr[(size_t)p * 256];
  avg[(size_t)(g0 + b) * 256 + j] = sum * (1.0f / 99.0f);
}

// ---------------------------------------------------------------------------
extern "C" void kernel_launch(void* const* d_in, const int* in_sizes, int n_in,
                              void* d_out, int out_size, void* d_ws, size_t ws_size,
                              hipStream_t stream) {
  const float* x       = (const float*)d_in[0];
  const int*   ei      = (const int*)d_in[1];
  const int*   et      = (const int*)d_in[2];
  const float* ggnn_W  = (const float*)d_in[3];
  const float* ggnn_b  = (const float*)d_in[4];
  const float* gru_Wih = (const float*)d_in[5];
  const float* gru_Whh = (const float*)d_in[6];
  const float* gru_bih = (const float*)d_in[7];
  const float* gru_bhh = (const float*)d_in[8];
  const float* conv1_w = (const float*)d_in[9];
  const float* conv1_b = (const float*)d_in[10];
  const float* conv2_w = (const float*)d_in[11];
  const float* conv2_b = (const float*)d_in[12];
  const float* cconv1_w = (const float*)d_in[13];
  const float* cconv1_b = (const float*)d_in[14];
  const float* cconv2_w = (const float*)d_in[15];
  const float* cconv2_b = (const float*)d_in[16];
  const float* mlp_y_w = (const float*)d_in[17];
  const float* mlp_y_b = (const float*)d_in[18];
  const float* mlp_z_w = (const float*)d_in[19];
  const float* mlp_z_b = (const float*)d_in[20];
  const float* ml_l1_w = (const float*)d_in[21];
  const float* ml_l1_b = (const float*)d_in[22];
  const float* ml_f1_w = (const float*)d_in[23];
  const float* ml_f1_b = (const float*)d_in[24];
  const float* ml_f2_w = (const float*)d_in[25];
  const float* ml_f2_b = (const float*)d_in[26];
  const float* cls_w   = (const float*)d_in[27];
  const float* cls_b   = (const float*)d_in[28];
  float* out = (float*)d_out;

  // ---------------- workspace layout (bytes) ----------------
  char* base = (char*)d_ws;
  size_t off = 0;
  auto alloc = [&](size_t bytes) { char* p = base + off; off += (bytes + 15) & ~(size_t)15; return p; };
  unsigned short* s2  = (unsigned short*)alloc(124518400); // [NN,608] bf16
  unsigned short* hb1 = (unsigned short*)alloc(40960000);  // mirror buf (odd)
  unsigned short* hb0 = (unsigned short*)alloc(40960000);  // mirror buf (even/final)
  int* eidx    = (int*)alloc(3276800);
  int* rowptr  = (int*)alloc(409604);
  float* cnt2  = (float*)alloc(819200);
  short* WPF   = (short*)alloc(1089536);
  short* WPwc  = (short*)alloc(229376);
  short* WPc1  = (short*)alloc(311296);
  short* WPcc1 = (short*)alloc(737280);
  short* WPc2  = (short*)alloc(114688);
  short* WPcc2 = (short*)alloc(245760);
  short* WPmy  = (short*)alloc(114688);
  short* WPmz  = (short*)alloc(163840);
  short* WPl1  = (short*)alloc(65536);
  short* WPf1  = (short*)alloc(32768);
  short* WPf2  = (short*)alloc(16384);
  short* WPcls = (short*)alloc(32768);
  float* bb  = (float*)alloc(3584);
  float* tt0 = (float*)alloc(3584);
  float* tt1 = (float*)alloc(3584);
  float* avg = (float*)alloc(262144);
  float* h1b = (float*)alloc(131072);
  float* hf1 = (float*)alloc(65536);
  const size_t persist = off;
  float* h = (float*)alloc(81920000);          // optional fp32 GRU carry
  const bool has_h = (ws_size >= off);

  const int fill_blocks = (out_size + 255) / 256;
  if (ws_size < persist) {
    fill_kernel<<<fill_blocks, 256, 0, stream>>>(out, out_size,
                                                 -(float)(ws_size >> 20));
    return;
  }
  float* hptr = has_h ? h : nullptr;

  // setup-only scratch aliased into s2 (dead before first gather)
  char* ali = (char*)s2;
  float* Wcat2 = (float*)(ali);            // 320,000
  float* M1f   = (float*)(ali + 320000);   // 960,000
  float* WFD   = (float*)(ali + 1280000);  // 1,920,000
  float* ta    = (float*)(ali + 3200000);  // 4,800
  int* cnt     = (int*)(ali + 3204800);    // 409,600
  int* ex      = (int*)(ali + 3614400);    // 409,600
  int* bsum    = (int*)(ali + 4024000);    // 1,600
  int* fcur    = (int*)(ali + 4025600);    // 409,600

  fill_kernel<<<fill_blocks, 256, 0, stream>>>(out, out_size, 1.0e4f);

  // ---- setup ----
  pad_h_kernel<<<80000, 256, 0, stream>>>(x, hptr, hb0);
  hipMemsetAsync(cnt, 0, 409600, stream);
  hipMemsetAsync(fcur, 0, 409600, stream);
  hipMemsetAsync(cnt2, 0, 819200, stream);
  hist_kernel<<<3200, 256, 0, stream>>>(ei, cnt);
  scan1_kernel<<<400, 256, 0, stream>>>(cnt, ex, bsum);
  scan2_kernel<<<1, 64, 0, stream>>>(bsum, 400);
  scan3_kernel<<<400, 256, 0, stream>>>(ex, bsum, rowptr);
  fillcsr_kernel<<<3200, 256, 0, stream>>>(ei, et, rowptr, fcur, eidx);
  count_kernel<<<3200, 256, 0, stream>>>(ei, et, cnt2);

  auto packs = [&](const float* W, short* WP, int Nout, int K, int Ntp, int Kp, int CIN) {
    const int total = (Ntp >> 7) * (Kp >> 5) * 512;
    pack_w<<<(total + 255) / 256, 256, 0, stream>>>(W, WP, Nout, K, Ntp, Kp, CIN);
  };
  // M1 = Wih @ Wcat2^T  (600 x 400)
  wcat2_kernel<<<313, 256, 0, stream>>>(ggnn_W, Wcat2);
  packs(Wcat2, WPwc, 400, 200, 512, 224, 0);
  gemm_mfma<0, 0, 0, 0><<<dim3(4, 5), 256, 0, stream>>>(
      gru_Wih, nullptr, WPwc, nullptr, M1f, 600, 400, 200, 7);
  ta_kernel<<<5, 256, 0, stream>>>(gru_Wih, ggnn_b, ta);
  wfd_kernel<<<1875, 256, 0, stream>>>(M1f, gru_Whh, WFD);
  packs(WFD, WPF, 800, 600, 896, 608, 0);
  bbtt_kernel<<<4, 256, 0, stream>>>(gru_bih, gru_bhh, ta, bb, tt0, tt1);
  packs(conv1_w, WPc1,  200, 600, 256, 608, 200);
  packs(cconv1_w,WPcc1, 320, 960, 384, 960, 320);
  packs(conv2_w, WPc2,  200, 200, 256, 224, 0);
  packs(cconv2_w,WPcc2, 320, 320, 384, 320, 0);
  packs(mlp_y_w, WPmy,  256, 200, 256, 224, 0);
  packs(mlp_z_w, WPmz,  256, 320, 256, 320, 0);
  packs(ml_l1_w, WPl1,  128, 256, 128, 256, 0);
  packs(ml_f1_w, WPf1,   64, 128, 128, 128, 0);
  packs(ml_f2_w, WPf2,  128,  64, 128,  64, 0);
  packs(cls_w,   WPcls,   2, 128, 128, 128, 0);

  // ---- GGNN: 8 steps, 2 kernels each ----
  unsigned short* hbb[2] = {hb0, hb1};
  for (int step = 0; step < NSTEPS; step++) {
    unsigned short* hcur = hbb[step & 1];
    unsigned short* hnxt = hbb[(step & 1) ^ 1];
    gather_kernel<<<25600, 256, 0, stream>>>(hcur, rowptr, eidx, s2);
    ggnn_gemm_kernel<<<dim3(7, 800), 256, 0, stream>>>(
        s2, WPF, bb, tt0, tt1, cnt2, hcur, hptr, hnxt);
  }
  // final mirror is hb0 (after 8 steps)

  // ---- conv/pool/mlp readout, G=64 graphs per chunk (arena = s2) ----
  const int G = 64;
  float* b0  = (float*)s2;                         // G*398*320 fp32
  float* b1  = b0 + (size_t)G * 127360;            // G*198*320
  float* b2  = b1 + (size_t)G * 63360;             // G*198*320
  float* y2c = b2 + (size_t)G * 63360;             // G*99*200
  float* z2c = y2c + (size_t)G * 19800;            // G*99*320

  for (int g0 = 0; g0 < BB; g0 += G) {
    const unsigned short* hc = hb0 + (size_t)g0 * LL * HH;
    const float* xc = x + (size_t)g0 * LL * DD;
    const int M1 = G * 398, M2 = G * 198, M3 = G * 99;
    const int gy1 = (M1 + 127) / 128, gy2 = (M2 + 127) / 128, gy3 = (M3 + 127) / 128;
    gemm_mfma<1, 1, 0, 1><<<dim3(2, gy1), 256, 0, stream>>>(
        hc, nullptr, WPc1, conv1_b, b0, M1, 200, 600, 19);
    pool_kernel<<<(int)(((size_t)G * 198 * 200 + 255) / 256), 256, 0, stream>>>(
        b0, b1, G, 398, 198, 200, 3);
    gemm_mfma<0, 0, 0, 1><<<dim3(2, gy2), 256, 0, stream>>>(
        b1, nullptr, WPc2, conv2_b, b2, M2, 200, 200, 7);
    pool_kernel<<<(int)(((size_t)G * 99 * 200 + 255) / 256), 256, 0, stream>>>(
        b2, y2c, G, 198, 99, 200, 2);
    gemm_mfma<2, 1, 0, 1><<<dim3(3, gy1), 256, 0, stream>>>(
        hc, xc, WPcc1, cconv1_b, b0, M1, 320, 960, 30);
    pool_kernel<<<(int)(((size_t)G * 198 * 320 + 255) / 256), 256, 0, stream>>>(
        b0, b1, G, 398, 198, 320, 3);
    gemm_mfma<0, 0, 0, 1><<<dim3(3, gy2), 256, 0, stream>>>(
        b1, nullptr, WPcc2, cconv2_b, b2, M2, 320, 320, 10);
    pool_kernel<<<(int)(((size_t)G * 99 * 320 + 255) / 256), 256, 0, stream>>>(
        b2, z2c, G, 198, 99, 320, 2);
    gemm_mfma<0, 0, 0, 0><<<dim3(2, gy3), 256, 0, stream>>>(
        y2c, nullptr, WPmy, mlp_y_b, b0, M3, 256, 200, 7);
    gemm_mfma<0, 0, 0, 0><<<dim3(2, gy3), 256, 0, stream>>>(
        z2c, nullptr, WPmz, mlp_z_b, b1, M3, 256, 320, 10);
    prodmean_kernel<<<(G * 256 + 255) / 256, 256, 0, stream>>>(b0, b1, avg, g0, G);
  }

  // ---- head ----
  gemm_mfma<0, 0, 0, 1><<<dim3(1, 2), 256, 0, stream>>>(
      avg, nullptr, WPl1, ml_l1_b, h1b, 256, 128, 256, 8);
  gemm_mfma<0, 0, 0, 1><<<dim3(1, 2), 256, 0, stream>>>(
      h1b, nullptr, WPf1, ml_f1_b, hf1, 256, 64, 128, 4);
  gemm_mfma<0, 0, 0, 1><<<dim3(1, 2), 256, 0, stream>>>(
      hf1, nullptr, WPf2, ml_f2_b, out + 512, 256, 128, 64, 2);
  gemm_mfma<0, 0, 0, 0><<<dim3(1, 2), 256, 0, stream>>>(
      out + 512, nullptr, WPcls, cls_b, out, 256, 2, 128, 4);
}